// Round 10
// baseline (414.549 us; speedup 1.0000x reference)
//
#include <hip/hip_runtime.h>
#include <math.h>

#define HID 256
#define NEG_SLOPE 0.2f
#define LN_EPS 1e-5f

typedef __attribute__((ext_vector_type(4))) float f32x4;
typedef __attribute__((ext_vector_type(8))) short bf16x8;

__device__ __forceinline__ float bf2f_lo(unsigned int u) {
    union { unsigned int i; float f; } c; c.i = u << 16; return c.f;
}
__device__ __forceinline__ float bf2f_hi(unsigned int u) {
    union { unsigned int i; float f; } c; c.i = u & 0xffff0000u; return c.f;
}
__device__ __forceinline__ float bf2f_u(unsigned short u) {
    union { unsigned int i; float f; } c; c.i = ((unsigned int)u) << 16; return c.f;
}
__device__ __forceinline__ unsigned short f2bf(float f) {
    union { float f; unsigned int i; } c; c.f = f;
    unsigned int i = c.i;
    return (unsigned short)((i + 0x7fffu + ((i >> 16) & 1u)) >> 16);
}

// ---------------- deterministic sum of edge_weight ----------------
__global__ __launch_bounds__(256) void sum_stage1(const float* __restrict__ w, int n, float* __restrict__ partials) {
    __shared__ float sdata[4];
    float v = 0.f;
    for (int i = blockIdx.x * 256 + threadIdx.x; i < n; i += gridDim.x * 256) v += w[i];
    for (int o = 32; o; o >>= 1) v += __shfl_xor(v, o);
    if ((threadIdx.x & 63) == 0) sdata[threadIdx.x >> 6] = v;
    __syncthreads();
    if (threadIdx.x == 0) partials[blockIdx.x] = sdata[0] + sdata[1] + sdata[2] + sdata[3];
}

// block 0: finish edge-weight sum; block 1: per-layer edge coefficients
__global__ __launch_bounds__(256) void sum2_coeff_kernel(const float* __restrict__ partials, float* __restrict__ sumw,
                                                         const float* __restrict__ We1, const float* __restrict__ ae1,
                                                         const float* __restrict__ We2, const float* __restrict__ ae2,
                                                         float* __restrict__ c1, float* __restrict__ c2) {
    int t = threadIdx.x;
    if (blockIdx.x == 0) {
        __shared__ float sdata[4];
        float v = partials[t];
        for (int o = 32; o; o >>= 1) v += __shfl_xor(v, o);
        if ((t & 63) == 0) sdata[t >> 6] = v;
        __syncthreads();
        if (t == 0) *sumw = sdata[0] + sdata[1] + sdata[2] + sdata[3];
    } else {
        float v1 = We1[t] * ae1[t];
        float v2 = We2[t] * ae2[t];
        for (int o = 1; o < 64; o <<= 1) { v1 += __shfl_xor(v1, o); v2 += __shfl_xor(v2, o); }
        if ((t & 63) == 0) { c1[t >> 6] = v1; c2[t >> 6] = v2; }
    }
}

// ---------------- CSR build ----------------
__global__ __launch_bounds__(256) void hist_kernel(const int* __restrict__ ei, int E, int N, int* __restrict__ deg) {
    int e = blockIdx.x * 256 + threadIdx.x;
    if (e >= E + N) return;
    int d = (e < E) ? ei[E + e] : (e - E);
    atomicAdd(&deg[d], 1);
}

__global__ __launch_bounds__(256) void scan_reduce(const int* __restrict__ deg, int N, int* __restrict__ bsum) {
    __shared__ int sdata[4];
    int i = blockIdx.x * 256 + threadIdx.x;
    int v = (i < N) ? deg[i] : 0;
    for (int o = 32; o; o >>= 1) v += __shfl_xor(v, o);
    if ((threadIdx.x & 63) == 0) sdata[threadIdx.x >> 6] = v;
    __syncthreads();
    if (threadIdx.x == 0) bsum[blockIdx.x] = sdata[0] + sdata[1] + sdata[2] + sdata[3];
}

__global__ __launch_bounds__(256) void scan_bsums(const int* __restrict__ bsum, int NB, int* __restrict__ boff) {
    __shared__ int sm[256];
    int t = threadIdx.x;
    int v = (t < NB) ? bsum[t] : 0;
    sm[t] = v;
    __syncthreads();
    for (int o = 1; o < 256; o <<= 1) {
        int tv = (t >= o) ? sm[t - o] : 0;
        __syncthreads();
        sm[t] += tv;
        __syncthreads();
    }
    if (t < NB) boff[t] = sm[t] - v;
}

__global__ __launch_bounds__(256) void scan_apply(const int* __restrict__ deg, int N, const int* __restrict__ boff,
                                                  int* __restrict__ offs, int* __restrict__ cursor) {
    __shared__ int sm[256];
    int t = threadIdx.x;
    int i = blockIdx.x * 256 + t;
    int v = (i < N) ? deg[i] : 0;
    sm[t] = v;
    __syncthreads();
    for (int o = 1; o < 256; o <<= 1) {
        int tv = (t >= o) ? sm[t - o] : 0;
        __syncthreads();
        sm[t] += tv;
        __syncthreads();
    }
    if (i < N) {
        int e = boff[blockIdx.x] + sm[t] - v;
        offs[i] = e; cursor[i] = e;
        if (i == N - 1) offs[N] = boff[blockIdx.x] + sm[t];
    }
}

__global__ __launch_bounds__(256) void scatter_eid(const int* __restrict__ ei, int E, int N,
                                                   int* __restrict__ cursor, int* __restrict__ csr_eid) {
    int e = blockIdx.x * 256 + threadIdx.x;
    if (e >= E + N) return;
    int d = (e < E) ? ei[E + e] : (e - E);
    int pos = atomicAdd(&cursor[d], 1);
    csr_eid[pos] = e;
}

// Deterministic order restore: wave-per-node rank sort (keys = original edge ids, distinct).
__global__ __launch_bounds__(256) void sort_rank_kernel(const int* __restrict__ offs, int* __restrict__ eid, int N) {
    int lane = threadIdx.x & 63;
    int n = (blockIdx.x << 2) + (threadIdx.x >> 6);
    if (n >= N) return;
    int s0 = offs[n];
    int d = offs[n + 1] - s0;
    if (d <= 1) return;
    if (d <= 64) {
        int key = (lane < d) ? eid[s0 + lane] : 0x7fffffff;
        int rank = 0;
        for (int j = 0; j < d; j++) {
            int kj = __shfl(key, j);
            rank += (kj < key) ? 1 : 0;
        }
        if (lane < d) eid[s0 + rank] = key;
    } else if (lane == 0) {
        for (int i = s0 + 1; i < s0 + d; i++) {
            int ke = eid[i];
            int j = i - 1;
            while (j >= s0 && eid[j] > ke) { eid[j + 1] = eid[j]; j--; }
            eid[j + 1] = ke;
        }
    }
}

__global__ __launch_bounds__(256) void csr_gather(const int* __restrict__ eid, const int* __restrict__ ei,
                                                  const float* __restrict__ ew, const float* __restrict__ sumw,
                                                  int E, int EN, int* __restrict__ csr_src, float* __restrict__ csr_w) {
    int i = blockIdx.x * 256 + threadIdx.x;
    if (i >= EN) return;
    int e = eid[i];
    if (e < E) { csr_src[i] = ei[e]; csr_w[i] = ew[e]; }
    else       { csr_src[i] = e - E; csr_w[i] = *sumw / (float)E; }
}

// ---------------- both W: fp32 [256][K] -> bf16 tiled [ks8][kg4][col256][e8], zero-pad K->256 ----------------
__global__ __launch_bounds__(256) void cvt_w_both(const float* __restrict__ W1, const float* __restrict__ W2,
                                                  unsigned short* __restrict__ o1, unsigned short* __restrict__ o2,
                                                  int K1) {
    int b = blockIdx.x, k = threadIdx.x;
    const float* in = (b < 256) ? W1 : W2;
    unsigned short* out = (b < 256) ? o1 : o2;
    int K = (b < 256) ? K1 : 256;
    int col = b & 255;
    float v = (k < K) ? in[(size_t)col * K + k] : 0.f;
    out[((k >> 5) * 4 + ((k >> 3) & 3)) * 2048 + col * 8 + (k & 7)] = f2bf(v);
}

// ---------------- bf16 MFMA GEMM (K=256); AF32: A read directly from fp32 (K_in cols, zero-padded) ----------------
template<bool AF32>
__global__ __launch_bounds__(256) void gemm_mfma(
    const unsigned short* __restrict__ A16, const float* __restrict__ Af, int K_in,
    const unsigned short* __restrict__ Bt16, int M,
    const float* __restrict__ asf, const float* __restrict__ adf,
    unsigned short* __restrict__ C16, float* __restrict__ as_out, float* __restrict__ ad_out)
{
    __shared__ __align__(16) unsigned short Asl[64 * 256];    // 32 KB
    __shared__ __align__(16) unsigned short Bsl[4 * 256 * 8]; // 16 KB
    int t = threadIdx.x;
    int lane = t & 63, w = t >> 6;
    int wm = w >> 1, wn = w & 1;
    int row0 = blockIdx.x << 6;

    // stage A once (XOR-swizzled); AF32 converts fp32 -> bf16 in-flight
#pragma unroll
    for (int j = 0; j < 8; j++) {
        int idx = j * 256 + t;
        int row = idx >> 5;
        int gr = row0 + row;
        uint4 va = {0u, 0u, 0u, 0u};
        if (AF32) {
            unsigned short h[8];
            int c0 = (idx & 31) * 8;
            int rem = K_in - c0;
            if (gr < M && rem > 0) {
                const float* xr = Af + (size_t)gr * K_in + c0;
#pragma unroll
                for (int q = 0; q < 8; q++) h[q] = (q < rem) ? f2bf(xr[q]) : (unsigned short)0;
            } else {
#pragma unroll
                for (int q = 0; q < 8; q++) h[q] = 0;
            }
            va.x = ((unsigned int)h[1] << 16) | h[0];
            va.y = ((unsigned int)h[3] << 16) | h[2];
            va.z = ((unsigned int)h[5] << 16) | h[4];
            va.w = ((unsigned int)h[7] << 16) | h[6];
        } else {
            if (gr < M) va = *(const uint4*)(A16 + (size_t)gr * 256 + (idx & 31) * 8);
        }
        int byte = (idx << 4) ^ ((row & 7) << 4);
        *(uint4*)((char*)Asl + byte) = va;
    }

    f32x4 acc[2][8];
#pragma unroll
    for (int i = 0; i < 2; i++)
#pragma unroll
        for (int j = 0; j < 8; j++) acc[i][j] = (f32x4){0.f, 0.f, 0.f, 0.f};

    int kg = lane >> 4, fr = lane & 15;
    int arow0 = wm * 32 + fr, arow1 = arow0 + 16;
    int sw0 = (arow0 & 7) << 4, sw1 = (arow1 & 7) << 4;
    __syncthreads();

    for (int ks = 0; ks < 8; ks++) {
#pragma unroll
        for (int j = 0; j < 4; j++) {
            uint4 vb = *(const uint4*)(Bt16 + (size_t)ks * 8192 + (size_t)(j * 256 + t) * 8);
            *(uint4*)((char*)Bsl + j * 4096 + ((t << 4) ^ (j << 4))) = vb;
        }
        __syncthreads();
        bf16x8 a0 = *(const bf16x8*)((const char*)Asl + (((arow0 << 9) + (ks << 6) + (kg << 4)) ^ sw0));
        bf16x8 a1 = *(const bf16x8*)((const char*)Asl + (((arow1 << 9) + (ks << 6) + (kg << 4)) ^ sw1));
#pragma unroll
        for (int nf = 0; nf < 8; nf++) {
            int col = wn * 128 + nf * 16 + fr;
            bf16x8 bv = *(const bf16x8*)((const char*)Bsl + (kg << 12) + (((col << 4)) ^ (kg << 4)));
            acc[0][nf] = __builtin_amdgcn_mfma_f32_16x16x32_bf16(a0, bv, acc[0][nf], 0, 0, 0);
            acc[1][nf] = __builtin_amdgcn_mfma_f32_16x16x32_bf16(a1, bv, acc[1][nf], 0, 0, 0);
        }
        __syncthreads();
    }

    // C write (bf16); C/D frag: col = fr, row = kg*4 + j
#pragma unroll
    for (int mf = 0; mf < 2; mf++)
#pragma unroll
        for (int j = 0; j < 4; j++) {
            int gr = row0 + wm * 32 + mf * 16 + kg * 4 + j;
            if (gr < M) {
#pragma unroll
                for (int nf = 0; nf < 8; nf++)
                    C16[(size_t)gr * 256 + wn * 128 + nf * 16 + fr] = f2bf(acc[mf][nf][j]);
            }
        }
    // alpha epilogue (exact per-row dots with a_s/a_d)
    float asv[8], adv[8];
#pragma unroll
    for (int nf = 0; nf < 8; nf++) {
        int col = wn * 128 + nf * 16 + fr;
        asv[nf] = asf[col]; adv[nf] = adf[col];
    }
#pragma unroll
    for (int mf = 0; mf < 2; mf++)
#pragma unroll
        for (int j = 0; j < 4; j++)
#pragma unroll
            for (int hh = 0; hh < 2; hh++) {
                float ps = 0.f, pd = 0.f;
#pragma unroll
                for (int q = 0; q < 4; q++) {
                    int nf = hh * 4 + q;
                    ps += acc[mf][nf][j] * asv[nf];
                    pd += acc[mf][nf][j] * adv[nf];
                }
#pragma unroll
                for (int o = 1; o < 16; o <<= 1) { ps += __shfl_xor(ps, o); pd += __shfl_xor(pd, o); }
                if (fr == 0) {
                    int gr = row0 + wm * 32 + mf * 16 + kg * 4 + j;
                    if (gr < M) {
                        as_out[gr * 4 + wn * 2 + hh] = ps;
                        ad_out[gr * 4 + wn * 2 + hh] = pd;
                    }
                }
            }
}

// ---------------- fused GAT + bias + LN + ELU -> bf16 out; software-pipelined gather ----------------
#define ACC8(u, q) do { \
    acc0 += (q) * bf2f_lo((u).x); acc1 += (q) * bf2f_hi((u).x); \
    acc2 += (q) * bf2f_lo((u).y); acc3 += (q) * bf2f_hi((u).y); \
    acc4 += (q) * bf2f_lo((u).z); acc5 += (q) * bf2f_hi((u).z); \
    acc6 += (q) * bf2f_lo((u).w); acc7 += (q) * bf2f_hi((u).w); } while (0)

__global__ __launch_bounds__(256) void gat_kernel(
    const unsigned short* __restrict__ xp16, const int* __restrict__ offs,
    const int* __restrict__ csr_src, const float* __restrict__ csr_w,
    const float* __restrict__ as_, const float* __restrict__ ad_,
    const float* __restrict__ cvec, const float* __restrict__ bias,
    const float* __restrict__ ln_g, const float* __restrict__ ln_b,
    int N, unsigned short* __restrict__ out16) {
    __shared__ float p_lds[4][256];
    __shared__ int   s_lds[4][64];
    int lane = threadIdx.x & 63;
    int wid = threadIdx.x >> 6;
    int n = (blockIdx.x << 2) + wid;
    if (n >= N) return;
    int start = offs[n], end = offs[n + 1];
    int e0 = lane >> 5;
    int colb = lane & 31;
    int hq2 = colb >> 3;
    const unsigned short* xbase = xp16 + (size_t)colb * 8;
    float4 adv = *(const float4*)(ad_ + (size_t)n * 4);
    float c0 = cvec[0], c1 = cvec[1], c2 = cvec[2], c3 = cvec[3];
    float m = -INFINITY, dn = 0.f;
    float acc0 = 0, acc1 = 0, acc2 = 0, acc3 = 0, acc4 = 0, acc5 = 0, acc6 = 0, acc7 = 0;

    for (int base = start; base < end; base += 64) {
        int idx = base + lane;
        bool act = idx < end;
        int s = act ? csr_src[idx] : 0;
        float w = act ? csr_w[idx] : 0.f;
        float4 av = *(const float4*)(as_ + (size_t)s * 4);
        float l0 = av.x + adv.x + w * c0; l0 = l0 >= 0.f ? l0 : NEG_SLOPE * l0;
        float l1 = av.y + adv.y + w * c1; l1 = l1 >= 0.f ? l1 : NEG_SLOPE * l1;
        float l2 = av.z + adv.z + w * c2; l2 = l2 >= 0.f ? l2 : NEG_SLOPE * l2;
        float l3 = av.w + adv.w + w * c3; l3 = l3 >= 0.f ? l3 : NEG_SLOPE * l3;
        float lm = fmaxf(fmaxf(l0, l1), fmaxf(l2, l3));
        if (!act) lm = -INFINITY;
        for (int o = 32; o; o >>= 1) lm = fmaxf(lm, __shfl_xor(lm, o));
        float nm = fmaxf(m, lm);
        float sc = __expf(m - nm);
        m = nm;
        dn *= sc;
        acc0 *= sc; acc1 *= sc; acc2 *= sc; acc3 *= sc;
        acc4 *= sc; acc5 *= sc; acc6 *= sc; acc7 *= sc;
        float p0 = act ? __expf(l0 - m) : 0.f;
        float p1 = act ? __expf(l1 - m) : 0.f;
        float p2 = act ? __expf(l2 - m) : 0.f;
        float p3 = act ? __expf(l3 - m) : 0.f;
        float4 pv = { p0, p1, p2, p3 };
        *(float4*)&p_lds[wid][lane << 2] = pv;
        s_lds[wid][lane] = s;
        int cnt = end - base; if (cnt > 64) cnt = 64;
        int k = 0;
        if (k + 8 <= cnt) {
            // prologue: issue group 0
            int i0 = e0, i1 = 2 + e0, i2 = 4 + e0, i3 = 6 + e0;
            int s0 = s_lds[wid][i0], s1 = s_lds[wid][i1], s2 = s_lds[wid][i2], s3 = s_lds[wid][i3];
            uint4 u0 = *(const uint4*)(xbase + (size_t)s0 * 256);
            uint4 u1 = *(const uint4*)(xbase + (size_t)s1 * 256);
            uint4 u2 = *(const uint4*)(xbase + (size_t)s2 * 256);
            uint4 u3 = *(const uint4*)(xbase + (size_t)s3 * 256);
            float q0 = p_lds[wid][(i0 << 2) + hq2];
            float q1 = p_lds[wid][(i1 << 2) + hq2];
            float q2 = p_lds[wid][(i2 << 2) + hq2];
            float q3 = p_lds[wid][(i3 << 2) + hq2];
            for (k = 8; k + 8 <= cnt; k += 8) {
                // issue next group's loads before consuming current
                int j0 = k + e0, j1 = k + 2 + e0, j2 = k + 4 + e0, j3 = k + 6 + e0;
                int t0 = s_lds[wid][j0], t1 = s_lds[wid][j1], t2 = s_lds[wid][j2], t3 = s_lds[wid][j3];
                uint4 v0 = *(const uint4*)(xbase + (size_t)t0 * 256);
                uint4 v1 = *(const uint4*)(xbase + (size_t)t1 * 256);
                uint4 v2 = *(const uint4*)(xbase + (size_t)t2 * 256);
                uint4 v3 = *(const uint4*)(xbase + (size_t)t3 * 256);
                float r0 = p_lds[wid][(j0 << 2) + hq2];
                float r1 = p_lds[wid][(j1 << 2) + hq2];
                float r2 = p_lds[wid][(j2 << 2) + hq2];
                float r3 = p_lds[wid][(j3 << 2) + hq2];
                dn += q0 + q1 + q2 + q3;
                ACC8(u0, q0); ACC8(u1, q1); ACC8(u2, q2); ACC8(u3, q3);
                u0 = v0; u1 = v1; u2 = v2; u3 = v3;
                q0 = r0; q1 = r1; q2 = r2; q3 = r3;
            }
            dn += q0 + q1 + q2 + q3;
            ACC8(u0, q0); ACC8(u1, q1); ACC8(u2, q2); ACC8(u3, q3);
        }
        for (; k < cnt; k += 2) {
            int i = k + e0;
            bool v = i < cnt;
            int si = s_lds[wid][v ? i : 0];
            float qi = v ? p_lds[wid][(i << 2) + hq2] : 0.f;
            uint4 u = *(const uint4*)(xbase + (size_t)si * 256);
            dn += qi;
            ACC8(u, qi);
        }
    }
    acc0 += __shfl_xor(acc0, 32); acc1 += __shfl_xor(acc1, 32);
    acc2 += __shfl_xor(acc2, 32); acc3 += __shfl_xor(acc3, 32);
    acc4 += __shfl_xor(acc4, 32); acc5 += __shfl_xor(acc5, 32);
    acc6 += __shfl_xor(acc6, 32); acc7 += __shfl_xor(acc7, 32);
    dn += __shfl_xor(dn, 32);
    float inv = 1.f / dn;
    int cb8 = colb << 3;
    float4 bA = *(const float4*)(bias + cb8);
    float4 bB = *(const float4*)(bias + cb8 + 4);
    float o0 = acc0 * inv + bA.x, o1 = acc1 * inv + bA.y, o2 = acc2 * inv + bA.z, o3 = acc3 * inv + bA.w;
    float o4 = acc4 * inv + bB.x, o5 = acc5 * inv + bB.y, o6 = acc6 * inv + bB.z, o7 = acc7 * inv + bB.w;
    float part = ((o0 + o1) + (o2 + o3)) + ((o4 + o5) + (o6 + o7));
    for (int o = 16; o; o >>= 1) part += __shfl_xor(part, o);
    float mu = part * (1.f / 256.f);
    float d0 = o0 - mu, d1 = o1 - mu, d2 = o2 - mu, d3 = o3 - mu;
    float d4 = o4 - mu, d5 = o5 - mu, d6 = o6 - mu, d7 = o7 - mu;
    float vpart = ((d0 * d0 + d1 * d1) + (d2 * d2 + d3 * d3)) + ((d4 * d4 + d5 * d5) + (d6 * d6 + d7 * d7));
    for (int o = 16; o; o >>= 1) vpart += __shfl_xor(vpart, o);
    float rstd = rsqrtf(vpart * (1.f / 256.f) + LN_EPS);
    float4 gA = *(const float4*)(ln_g + cb8), gB = *(const float4*)(ln_g + cb8 + 4);
    float4 eA = *(const float4*)(ln_b + cb8), eB = *(const float4*)(ln_b + cb8 + 4);
    float y0 = d0 * rstd * gA.x + eA.x; y0 = y0 > 0.f ? y0 : __expf(y0) - 1.f;
    float y1 = d1 * rstd * gA.y + eA.y; y1 = y1 > 0.f ? y1 : __expf(y1) - 1.f;
    float y2 = d2 * rstd * gA.z + eA.z; y2 = y2 > 0.f ? y2 : __expf(y2) - 1.f;
    float y3 = d3 * rstd * gA.w + eA.w; y3 = y3 > 0.f ? y3 : __expf(y3) - 1.f;
    float y4 = d4 * rstd * gB.x + eB.x; y4 = y4 > 0.f ? y4 : __expf(y4) - 1.f;
    float y5 = d5 * rstd * gB.y + eB.y; y5 = y5 > 0.f ? y5 : __expf(y5) - 1.f;
    float y6 = d6 * rstd * gB.z + eB.z; y6 = y6 > 0.f ? y6 : __expf(y6) - 1.f;
    float y7 = d7 * rstd * gB.w + eB.w; y7 = y7 > 0.f ? y7 : __expf(y7) - 1.f;
    if (lane < 32) {
        uint4 ov;
        ov.x = ((unsigned int)f2bf(y1) << 16) | f2bf(y0);
        ov.y = ((unsigned int)f2bf(y3) << 16) | f2bf(y2);
        ov.z = ((unsigned int)f2bf(y5) << 16) | f2bf(y4);
        ov.w = ((unsigned int)f2bf(y7) << 16) | f2bf(y6);
        *(uint4*)(out16 + (size_t)n * HID + cb8) = ov;
    }
}

// ---------------- batch mean pool (bf16 input) ----------------
__device__ __forceinline__ int lower_bound_i(const int* a, int n, int key) {
    int lo = 0, hi = n;
    while (lo < hi) { int mid = (lo + hi) >> 1; if (a[mid] < key) lo = mid + 1; else hi = mid; }
    return lo;
}

__global__ __launch_bounds__(256) void pool_kernel(const unsigned short* __restrict__ h, const int* __restrict__ batch,
                                                   int N, float* __restrict__ out) {
    int b = blockIdx.x;
    int lo = lower_bound_i(batch, N, b);
    int hi = lower_bound_i(batch, N, b + 1);
    float acc = 0.f;
    for (int n = lo; n < hi; n++) acc += bf2f_u(h[(size_t)n * HID + threadIdx.x]);
    out[(size_t)b * HID + threadIdx.x] = acc / fmaxf((float)(hi - lo), 1.f);
}

extern "C" void kernel_launch(void* const* d_in, const int* in_sizes, int n_in,
                              void* d_out, int out_size, void* d_ws, size_t ws_size,
                              hipStream_t stream) {
    const float* x    = (const float*)d_in[0];
    const int*   ei   = (const int*)d_in[1];
    const float* ew   = (const float*)d_in[2];
    const int*   batch= (const int*)d_in[3];
    const float* W1   = (const float*)d_in[4];
    const float* as1  = (const float*)d_in[5];
    const float* ad1  = (const float*)d_in[6];
    const float* ae1  = (const float*)d_in[7];
    const float* We1  = (const float*)d_in[8];
    const float* b1   = (const float*)d_in[9];
    const float* W2   = (const float*)d_in[10];
    const float* as2  = (const float*)d_in[11];
    const float* ad2  = (const float*)d_in[12];
    const float* ae2  = (const float*)d_in[13];
    const float* We2  = (const float*)d_in[14];
    const float* b2   = (const float*)d_in[15];
    const float* ln1g = (const float*)d_in[16];
    const float* ln1b = (const float*)d_in[17];
    const float* ln2g = (const float*)d_in[18];
    const float* ln2b = (const float*)d_in[19];

    int N = in_sizes[3];
    int E = in_sizes[2];
    int FIN = in_sizes[0] / N;
    int EN = E + N;
    int B = out_size / HID;
    float* outp = (float*)d_out;
    int NB = (N + 255) / 256;

    char* ws = (char*)d_ws;
    size_t off = 0;
    auto alloc = [&](size_t bytes) { void* p = ws + off; off = (off + bytes + 255) & ~(size_t)255; return p; };
    float* sumw    = (float*)alloc(4);
    int*   deg     = (int*)  alloc((size_t)N * 4);           // zeroed region = [0, 256 + N*4)
    size_t zero_bytes = 256 + (size_t)N * 4;
    float* partials= (float*)alloc(256 * 4);
    int*   bsum    = (int*)  alloc(256 * 4);
    int*   boff    = (int*)  alloc(256 * 4);
    int*   offs    = (int*)  alloc((size_t)(N + 1) * 4);
    int*   cursor  = (int*)  alloc((size_t)N * 4);
    int*   csr_eid = (int*)  alloc((size_t)EN * 4);
    int*   csr_src = (int*)  alloc((size_t)EN * 4);
    float* csr_w   = (float*)alloc((size_t)EN * 4);
    float* asb     = (float*)alloc((size_t)N * 4 * 4);
    float* adb     = (float*)alloc((size_t)N * 4 * 4);
    float* cc      = (float*)alloc(64);
    unsigned short* w1_16 = (unsigned short*)alloc((size_t)HID * HID * 2);
    unsigned short* w2_16 = (unsigned short*)alloc((size_t)HID * HID * 2);
    unsigned short* x16   = (unsigned short*)alloc((size_t)N * HID * 2);  // h1 -> h2 (reused)
    unsigned short* xp16  = (unsigned short*)alloc((size_t)N * HID * 2);
    (void)ws_size; (void)n_in;

    (void)hipMemsetAsync(d_ws, 0, zero_bytes, stream);
    sum_stage1<<<256, 256, 0, stream>>>(ew, E, partials);
    sum2_coeff_kernel<<<2, 256, 0, stream>>>(partials, sumw, We1, ae1, We2, ae2, cc, cc + 4);
    hist_kernel<<<(EN + 255) / 256, 256, 0, stream>>>(ei, E, N, deg);
    scan_reduce<<<NB, 256, 0, stream>>>(deg, N, bsum);
    scan_bsums<<<1, 256, 0, stream>>>(bsum, NB, boff);
    scan_apply<<<NB, 256, 0, stream>>>(deg, N, boff, offs, cursor);
    scatter_eid<<<(EN + 255) / 256, 256, 0, stream>>>(ei, E, N, cursor, csr_eid);
    sort_rank_kernel<<<(N + 3) / 4, 256, 0, stream>>>(offs, csr_eid, N);
    csr_gather<<<(EN + 255) / 256, 256, 0, stream>>>(csr_eid, ei, ew, sumw, E, EN, csr_src, csr_w);

    // weight conversion (x conversion fused into layer-1 GEMM)
    cvt_w_both<<<512, 256, 0, stream>>>(W1, W2, w1_16, w2_16, FIN);

    int MB = (N + 63) / 64;
    // layer 1 (A = fp32 x, converted in staging)
    gemm_mfma<true><<<MB, 256, 0, stream>>>(nullptr, x, FIN, w1_16, N, as1, ad1, xp16, asb, adb);
    gat_kernel<<<(N + 3) / 4, 256, 0, stream>>>(xp16, offs, csr_src, csr_w, asb, adb, cc, b1, ln1g, ln1b, N, x16);
    // layer 2 (A = layer-1 output, bf16)
    gemm_mfma<false><<<MB, 256, 0, stream>>>(x16, nullptr, 256, w2_16, N, as2, ad2, xp16, asb, adb);
    gat_kernel<<<(N + 3) / 4, 256, 0, stream>>>(xp16, offs, csr_src, csr_w, asb, adb, cc + 4, b2, ln2g, ln2b, N, x16);
    // pool
    pool_kernel<<<B, 256, 0, stream>>>(x16, batch, N, outp);
}

// Round 11
// 391.650 us; speedup vs baseline: 1.0585x; 1.0585x over previous
//
#include <hip/hip_runtime.h>
#include <math.h>

#define HID 256
#define NEG_SLOPE 0.2f
#define LN_EPS 1e-5f

typedef __attribute__((ext_vector_type(4))) float f32x4;
typedef __attribute__((ext_vector_type(8))) short bf16x8;
typedef __attribute__((address_space(3))) unsigned char lds_b;
typedef const __attribute__((address_space(1))) unsigned char glob_b;

__device__ __forceinline__ float bf2f_lo(unsigned int u) {
    union { unsigned int i; float f; } c; c.i = u << 16; return c.f;
}
__device__ __forceinline__ float bf2f_hi(unsigned int u) {
    union { unsigned int i; float f; } c; c.i = u & 0xffff0000u; return c.f;
}
__device__ __forceinline__ float bf2f_u(unsigned short u) {
    union { unsigned int i; float f; } c; c.i = ((unsigned int)u) << 16; return c.f;
}
__device__ __forceinline__ unsigned short f2bf(float f) {
    union { float f; unsigned int i; } c; c.f = f;
    unsigned int i = c.i;
    return (unsigned short)((i + 0x7fffu + ((i >> 16) & 1u)) >> 16);
}

// ---------------- deterministic sum of edge_weight ----------------
__global__ __launch_bounds__(256) void sum_stage1(const float* __restrict__ w, int n, float* __restrict__ partials) {
    __shared__ float sdata[4];
    float v = 0.f;
    for (int i = blockIdx.x * 256 + threadIdx.x; i < n; i += gridDim.x * 256) v += w[i];
    for (int o = 32; o; o >>= 1) v += __shfl_xor(v, o);
    if ((threadIdx.x & 63) == 0) sdata[threadIdx.x >> 6] = v;
    __syncthreads();
    if (threadIdx.x == 0) partials[blockIdx.x] = sdata[0] + sdata[1] + sdata[2] + sdata[3];
}

// block 0: finish edge-weight sum; block 1: per-layer edge coefficients
__global__ __launch_bounds__(256) void sum2_coeff_kernel(const float* __restrict__ partials, float* __restrict__ sumw,
                                                         const float* __restrict__ We1, const float* __restrict__ ae1,
                                                         const float* __restrict__ We2, const float* __restrict__ ae2,
                                                         float* __restrict__ c1, float* __restrict__ c2) {
    int t = threadIdx.x;
    if (blockIdx.x == 0) {
        __shared__ float sdata[4];
        float v = partials[t];
        for (int o = 32; o; o >>= 1) v += __shfl_xor(v, o);
        if ((t & 63) == 0) sdata[t >> 6] = v;
        __syncthreads();
        if (t == 0) *sumw = sdata[0] + sdata[1] + sdata[2] + sdata[3];
    } else {
        float v1 = We1[t] * ae1[t];
        float v2 = We2[t] * ae2[t];
        for (int o = 1; o < 64; o <<= 1) { v1 += __shfl_xor(v1, o); v2 += __shfl_xor(v2, o); }
        if ((t & 63) == 0) { c1[t >> 6] = v1; c2[t >> 6] = v2; }
    }
}

// ---------------- CSR build ----------------
__global__ __launch_bounds__(256) void hist_kernel(const int* __restrict__ ei, int E, int N, int* __restrict__ deg) {
    int e = blockIdx.x * 256 + threadIdx.x;
    if (e >= E + N) return;
    int d = (e < E) ? ei[E + e] : (e - E);
    atomicAdd(&deg[d], 1);
}

__global__ __launch_bounds__(256) void scan_reduce(const int* __restrict__ deg, int N, int* __restrict__ bsum) {
    __shared__ int sdata[4];
    int i = blockIdx.x * 256 + threadIdx.x;
    int v = (i < N) ? deg[i] : 0;
    for (int o = 32; o; o >>= 1) v += __shfl_xor(v, o);
    if ((threadIdx.x & 63) == 0) sdata[threadIdx.x >> 6] = v;
    __syncthreads();
    if (threadIdx.x == 0) bsum[blockIdx.x] = sdata[0] + sdata[1] + sdata[2] + sdata[3];
}

__global__ __launch_bounds__(256) void scan_bsums(const int* __restrict__ bsum, int NB, int* __restrict__ boff) {
    __shared__ int sm[256];
    int t = threadIdx.x;
    int v = (t < NB) ? bsum[t] : 0;
    sm[t] = v;
    __syncthreads();
    for (int o = 1; o < 256; o <<= 1) {
        int tv = (t >= o) ? sm[t - o] : 0;
        __syncthreads();
        sm[t] += tv;
        __syncthreads();
    }
    if (t < NB) boff[t] = sm[t] - v;
}

__global__ __launch_bounds__(256) void scan_apply(const int* __restrict__ deg, int N, const int* __restrict__ boff,
                                                  int* __restrict__ offs, int* __restrict__ cursor) {
    __shared__ int sm[256];
    int t = threadIdx.x;
    int i = blockIdx.x * 256 + t;
    int v = (i < N) ? deg[i] : 0;
    sm[t] = v;
    __syncthreads();
    for (int o = 1; o < 256; o <<= 1) {
        int tv = (t >= o) ? sm[t - o] : 0;
        __syncthreads();
        sm[t] += tv;
        __syncthreads();
    }
    if (i < N) {
        int e = boff[blockIdx.x] + sm[t] - v;
        offs[i] = e; cursor[i] = e;
        if (i == N - 1) offs[N] = boff[blockIdx.x] + sm[t];
    }
}

__global__ __launch_bounds__(256) void scatter_eid(const int* __restrict__ ei, int E, int N,
                                                   int* __restrict__ cursor, int* __restrict__ csr_eid) {
    int e = blockIdx.x * 256 + threadIdx.x;
    if (e >= E + N) return;
    int d = (e < E) ? ei[E + e] : (e - E);
    int pos = atomicAdd(&cursor[d], 1);
    csr_eid[pos] = e;
}

// Deterministic order restore + CSR payload gather, fused.
// Wave per node: in-register rank sort of edge ids (d<=64), then direct gather to csr_src/csr_w.
__global__ __launch_bounds__(256) void sort_gather_kernel(const int* __restrict__ offs, int* __restrict__ eid,
                                                          const int* __restrict__ ei, const float* __restrict__ ew,
                                                          const float* __restrict__ sumw, int E, int N,
                                                          int* __restrict__ csr_src, float* __restrict__ csr_w) {
    int lane = threadIdx.x & 63;
    int n = (blockIdx.x << 2) + (threadIdx.x >> 6);
    if (n >= N) return;
    int s0 = offs[n];
    int d = offs[n + 1] - s0;
    if (d <= 0) return;
    if (d <= 64) {
        int key = (lane < d) ? eid[s0 + lane] : 0x7fffffff;
        int rank = 0;
        for (int j = 0; j < d; j++) {
            int kj = __shfl(key, j);
            rank += (kj < key) ? 1 : 0;
        }
        if (lane < d) {
            int s; float wv;
            if (key < E) { s = ei[key]; wv = ew[key]; }
            else         { s = key - E; wv = *sumw / (float)E; }
            csr_src[s0 + rank] = s;
            csr_w[s0 + rank] = wv;
        }
    } else {
        if (lane == 0) {
            for (int i = s0 + 1; i < s0 + d; i++) {
                int ke = eid[i];
                int j = i - 1;
                while (j >= s0 && eid[j] > ke) { eid[j + 1] = eid[j]; j--; }
                eid[j + 1] = ke;
            }
        }
        __builtin_amdgcn_wave_barrier();
        for (int i = lane; i < d; i += 64) {
            int e = eid[s0 + i];
            int s; float wv;
            if (e < E) { s = ei[e]; wv = ew[e]; }
            else       { s = e - E; wv = *sumw / (float)E; }
            csr_src[s0 + i] = s;
            csr_w[s0 + i] = wv;
        }
    }
}

// ---------------- x: fp32 -> bf16 row-major, zero-pad to 256 cols ----------------
__global__ __launch_bounds__(256) void cvt_pad_kernel(const float* __restrict__ in, unsigned short* __restrict__ out, int K) {
    int r = blockIdx.x, t = threadIdx.x;
    out[(size_t)r * 256 + t] = (t < K) ? f2bf(in[(size_t)r * K + t]) : (unsigned short)0;
}

// ---------------- both W: fp32 [256][K] -> bf16 pre-SWIZZLED LDS image, zero-pad K->256 ----------------
// File layout mirrors the gemm's B LDS tile exactly: per ks (16KB): byte = j*4096 + ((col<<4) ^ (j<<4)) + e*2
__global__ __launch_bounds__(256) void cvt_w_both(const float* __restrict__ W1, const float* __restrict__ W2,
                                                  unsigned short* __restrict__ o1, unsigned short* __restrict__ o2,
                                                  int K1) {
    int b = blockIdx.x, k = threadIdx.x;
    const float* in = (b < 256) ? W1 : W2;
    unsigned short* out = (b < 256) ? o1 : o2;
    int K = (b < 256) ? K1 : 256;
    int col = b & 255;
    float v = (k < K) ? in[(size_t)col * K + k] : 0.f;
    int ks = k >> 5, j = (k >> 3) & 3, e = k & 7;
    out[ks * 8192 + j * 2048 + ((((col << 4) ^ (j << 4))) >> 1) + e] = f2bf(v);
}

// ---------------- bf16 MFMA GEMM (K=256); B staged by linear global_load_lds from pre-swizzled file ----------------
__global__ __launch_bounds__(256) void gemm_mfma(
    const unsigned short* __restrict__ A16, const unsigned short* __restrict__ Bt16, int M,
    const float* __restrict__ asf, const float* __restrict__ adf,
    unsigned short* __restrict__ C16, float* __restrict__ as_out, float* __restrict__ ad_out)
{
    __shared__ __align__(16) unsigned short Asl[64 * 256];    // 32 KB
    __shared__ __align__(16) unsigned short Bsl[4 * 256 * 8]; // 16 KB
    int t = threadIdx.x;
    int lane = t & 63, w = t >> 6;
    int wm = w >> 1, wn = w & 1;
    int row0 = blockIdx.x << 6;

    // stage A once (XOR-swizzled write from registers)
#pragma unroll
    for (int j = 0; j < 8; j++) {
        int idx = j * 256 + t;
        int row = idx >> 5;
        int gr = row0 + row;
        uint4 va = {0u, 0u, 0u, 0u};
        if (gr < M) va = *(const uint4*)(A16 + (size_t)gr * 256 + (idx & 31) * 8);
        int byte = (idx << 4) ^ ((row & 7) << 4);
        *(uint4*)((char*)Asl + byte) = va;
    }

    f32x4 acc[2][8];
#pragma unroll
    for (int i = 0; i < 2; i++)
#pragma unroll
        for (int j = 0; j < 8; j++) acc[i][j] = (f32x4){0.f, 0.f, 0.f, 0.f};

    int kg = lane >> 4, fr = lane & 15;
    int arow0 = wm * 32 + fr, arow1 = arow0 + 16;
    int sw0 = (arow0 & 7) << 4, sw1 = (arow1 & 7) << 4;
    __syncthreads();

    for (int ks = 0; ks < 8; ks++) {
        // B tile: file is the LDS image -> pure linear DMA, 16B per lane, no VGPR round trip
#pragma unroll
        for (int j = 0; j < 4; j++) {
            __builtin_amdgcn_global_load_lds(
                (glob_b*)(Bt16 + (size_t)ks * 8192 + j * 2048 + t * 8),
                (lds_b*)((char*)Bsl + j * 4096 + t * 16),
                16, 0, 0);
        }
        __syncthreads();
        bf16x8 a0 = *(const bf16x8*)((const char*)Asl + (((arow0 << 9) + (ks << 6) + (kg << 4)) ^ sw0));
        bf16x8 a1 = *(const bf16x8*)((const char*)Asl + (((arow1 << 9) + (ks << 6) + (kg << 4)) ^ sw1));
#pragma unroll
        for (int nf = 0; nf < 8; nf++) {
            int col = wn * 128 + nf * 16 + fr;
            bf16x8 bv = *(const bf16x8*)((const char*)Bsl + (kg << 12) + (((col << 4)) ^ (kg << 4)));
            acc[0][nf] = __builtin_amdgcn_mfma_f32_16x16x32_bf16(a0, bv, acc[0][nf], 0, 0, 0);
            acc[1][nf] = __builtin_amdgcn_mfma_f32_16x16x32_bf16(a1, bv, acc[1][nf], 0, 0, 0);
        }
        __syncthreads();
    }

    // C write (bf16); C/D frag: col = fr, row = kg*4 + j
#pragma unroll
    for (int mf = 0; mf < 2; mf++)
#pragma unroll
        for (int j = 0; j < 4; j++) {
            int gr = row0 + wm * 32 + mf * 16 + kg * 4 + j;
            if (gr < M) {
#pragma unroll
                for (int nf = 0; nf < 8; nf++)
                    C16[(size_t)gr * 256 + wn * 128 + nf * 16 + fr] = f2bf(acc[mf][nf][j]);
            }
        }
    // alpha epilogue (exact per-row dots with a_s/a_d)
    float asv[8], adv[8];
#pragma unroll
    for (int nf = 0; nf < 8; nf++) {
        int col = wn * 128 + nf * 16 + fr;
        asv[nf] = asf[col]; adv[nf] = adf[col];
    }
#pragma unroll
    for (int mf = 0; mf < 2; mf++)
#pragma unroll
        for (int j = 0; j < 4; j++)
#pragma unroll
            for (int hh = 0; hh < 2; hh++) {
                float ps = 0.f, pd = 0.f;
#pragma unroll
                for (int q = 0; q < 4; q++) {
                    int nf = hh * 4 + q;
                    ps += acc[mf][nf][j] * asv[nf];
                    pd += acc[mf][nf][j] * adv[nf];
                }
#pragma unroll
                for (int o = 1; o < 16; o <<= 1) { ps += __shfl_xor(ps, o); pd += __shfl_xor(pd, o); }
                if (fr == 0) {
                    int gr = row0 + wm * 32 + mf * 16 + kg * 4 + j;
                    if (gr < M) {
                        as_out[gr * 4 + wn * 2 + hh] = ps;
                        ad_out[gr * 4 + wn * 2 + hh] = pd;
                    }
                }
            }
}

// ---------------- fused GAT + bias + LN + ELU -> bf16 out (round-9 gather shape) ----------------
#define ACC8(u, q) do { \
    acc0 += (q) * bf2f_lo((u).x); acc1 += (q) * bf2f_hi((u).x); \
    acc2 += (q) * bf2f_lo((u).y); acc3 += (q) * bf2f_hi((u).y); \
    acc4 += (q) * bf2f_lo((u).z); acc5 += (q) * bf2f_hi((u).z); \
    acc6 += (q) * bf2f_lo((u).w); acc7 += (q) * bf2f_hi((u).w); } while (0)

__global__ __launch_bounds__(256) void gat_kernel(
    const unsigned short* __restrict__ xp16, const int* __restrict__ offs,
    const int* __restrict__ csr_src, const float* __restrict__ csr_w,
    const float* __restrict__ as_, const float* __restrict__ ad_,
    const float* __restrict__ cvec, const float* __restrict__ bias,
    const float* __restrict__ ln_g, const float* __restrict__ ln_b,
    int N, unsigned short* __restrict__ out16) {
    __shared__ float p_lds[4][256];
    __shared__ int   s_lds[4][64];
    int lane = threadIdx.x & 63;
    int wid = threadIdx.x >> 6;
    int n = (blockIdx.x << 2) + wid;
    if (n >= N) return;
    int start = offs[n], end = offs[n + 1];
    int e0 = lane >> 5;
    int colb = lane & 31;
    int hq2 = colb >> 3;
    const unsigned short* xbase = xp16 + (size_t)colb * 8;
    float4 adv = *(const float4*)(ad_ + (size_t)n * 4);
    float c0 = cvec[0], c1 = cvec[1], c2 = cvec[2], c3 = cvec[3];
    float m = -INFINITY, dn = 0.f;
    float acc0 = 0, acc1 = 0, acc2 = 0, acc3 = 0, acc4 = 0, acc5 = 0, acc6 = 0, acc7 = 0;

    for (int base = start; base < end; base += 64) {
        int idx = base + lane;
        bool act = idx < end;
        int s = act ? csr_src[idx] : 0;
        float w = act ? csr_w[idx] : 0.f;
        float4 av = *(const float4*)(as_ + (size_t)s * 4);
        float l0 = av.x + adv.x + w * c0; l0 = l0 >= 0.f ? l0 : NEG_SLOPE * l0;
        float l1 = av.y + adv.y + w * c1; l1 = l1 >= 0.f ? l1 : NEG_SLOPE * l1;
        float l2 = av.z + adv.z + w * c2; l2 = l2 >= 0.f ? l2 : NEG_SLOPE * l2;
        float l3 = av.w + adv.w + w * c3; l3 = l3 >= 0.f ? l3 : NEG_SLOPE * l3;
        float lm = fmaxf(fmaxf(l0, l1), fmaxf(l2, l3));
        if (!act) lm = -INFINITY;
        for (int o = 32; o; o >>= 1) lm = fmaxf(lm, __shfl_xor(lm, o));
        float nm = fmaxf(m, lm);
        float sc = __expf(m - nm);
        m = nm;
        dn *= sc;
        acc0 *= sc; acc1 *= sc; acc2 *= sc; acc3 *= sc;
        acc4 *= sc; acc5 *= sc; acc6 *= sc; acc7 *= sc;
        float p0 = act ? __expf(l0 - m) : 0.f;
        float p1 = act ? __expf(l1 - m) : 0.f;
        float p2 = act ? __expf(l2 - m) : 0.f;
        float p3 = act ? __expf(l3 - m) : 0.f;
        float4 pv = { p0, p1, p2, p3 };
        *(float4*)&p_lds[wid][lane << 2] = pv;
        s_lds[wid][lane] = s;
        int cnt = end - base; if (cnt > 64) cnt = 64;
        int k = 0;
        for (; k + 8 <= cnt; k += 8) {
            int i0 = k + e0, i1 = k + 2 + e0, i2 = k + 4 + e0, i3 = k + 6 + e0;
            int s0 = s_lds[wid][i0], s1 = s_lds[wid][i1], s2 = s_lds[wid][i2], s3 = s_lds[wid][i3];
            uint4 u0 = *(const uint4*)(xbase + (size_t)s0 * 256);
            uint4 u1 = *(const uint4*)(xbase + (size_t)s1 * 256);
            uint4 u2 = *(const uint4*)(xbase + (size_t)s2 * 256);
            uint4 u3 = *(const uint4*)(xbase + (size_t)s3 * 256);
            float q0 = p_lds[wid][(i0 << 2) + hq2];
            float q1 = p_lds[wid][(i1 << 2) + hq2];
            float q2 = p_lds[wid][(i2 << 2) + hq2];
            float q3 = p_lds[wid][(i3 << 2) + hq2];
            dn += q0 + q1 + q2 + q3;
            ACC8(u0, q0); ACC8(u1, q1); ACC8(u2, q2); ACC8(u3, q3);
        }
        for (; k < cnt; k += 2) {
            int i = k + e0;
            bool v = i < cnt;
            int si = s_lds[wid][v ? i : 0];
            float qi = v ? p_lds[wid][(i << 2) + hq2] : 0.f;
            uint4 u = *(const uint4*)(xbase + (size_t)si * 256);
            dn += qi;
            ACC8(u, qi);
        }
    }
    acc0 += __shfl_xor(acc0, 32); acc1 += __shfl_xor(acc1, 32);
    acc2 += __shfl_xor(acc2, 32); acc3 += __shfl_xor(acc3, 32);
    acc4 += __shfl_xor(acc4, 32); acc5 += __shfl_xor(acc5, 32);
    acc6 += __shfl_xor(acc6, 32); acc7 += __shfl_xor(acc7, 32);
    dn += __shfl_xor(dn, 32);
    float inv = 1.f / dn;
    int cb8 = colb << 3;
    float4 bA = *(const float4*)(bias + cb8);
    float4 bB = *(const float4*)(bias + cb8 + 4);
    float o0 = acc0 * inv + bA.x, o1 = acc1 * inv + bA.y, o2 = acc2 * inv + bA.z, o3 = acc3 * inv + bA.w;
    float o4 = acc4 * inv + bB.x, o5 = acc5 * inv + bB.y, o6 = acc6 * inv + bB.z, o7 = acc7 * inv + bB.w;
    float part = ((o0 + o1) + (o2 + o3)) + ((o4 + o5) + (o6 + o7));
    for (int o = 16; o; o >>= 1) part += __shfl_xor(part, o);
    float mu = part * (1.f / 256.f);
    float d0 = o0 - mu, d1 = o1 - mu, d2 = o2 - mu, d3 = o3 - mu;
    float d4 = o4 - mu, d5 = o5 - mu, d6 = o6 - mu, d7 = o7 - mu;
    float vpart = ((d0 * d0 + d1 * d1) + (d2 * d2 + d3 * d3)) + ((d4 * d4 + d5 * d5) + (d6 * d6 + d7 * d7));
    for (int o = 16; o; o >>= 1) vpart += __shfl_xor(vpart, o);
    float rstd = rsqrtf(vpart * (1.f / 256.f) + LN_EPS);
    float4 gA = *(const float4*)(ln_g + cb8), gB = *(const float4*)(ln_g + cb8 + 4);
    float4 eA = *(const float4*)(ln_b + cb8), eB = *(const float4*)(ln_b + cb8 + 4);
    float y0 = d0 * rstd * gA.x + eA.x; y0 = y0 > 0.f ? y0 : __expf(y0) - 1.f;
    float y1 = d1 * rstd * gA.y + eA.y; y1 = y1 > 0.f ? y1 : __expf(y1) - 1.f;
    float y2 = d2 * rstd * gA.z + eA.z; y2 = y2 > 0.f ? y2 : __expf(y2) - 1.f;
    float y3 = d3 * rstd * gA.w + eA.w; y3 = y3 > 0.f ? y3 : __expf(y3) - 1.f;
    float y4 = d4 * rstd * gB.x + eB.x; y4 = y4 > 0.f ? y4 : __expf(y4) - 1.f;
    float y5 = d5 * rstd * gB.y + eB.y; y5 = y5 > 0.f ? y5 : __expf(y5) - 1.f;
    float y6 = d6 * rstd * gB.z + eB.z; y6 = y6 > 0.f ? y6 : __expf(y6) - 1.f;
    float y7 = d7 * rstd * gB.w + eB.w; y7 = y7 > 0.f ? y7 : __expf(y7) - 1.f;
    if (lane < 32) {
        uint4 ov;
        ov.x = ((unsigned int)f2bf(y1) << 16) | f2bf(y0);
        ov.y = ((unsigned int)f2bf(y3) << 16) | f2bf(y2);
        ov.z = ((unsigned int)f2bf(y5) << 16) | f2bf(y4);
        ov.w = ((unsigned int)f2bf(y7) << 16) | f2bf(y6);
        *(uint4*)(out16 + (size_t)n * HID + cb8) = ov;
    }
}

// ---------------- batch mean pool (bf16 input) ----------------
__device__ __forceinline__ int lower_bound_i(const int* a, int n, int key) {
    int lo = 0, hi = n;
    while (lo < hi) { int mid = (lo + hi) >> 1; if (a[mid] < key) lo = mid + 1; else hi = mid; }
    return lo;
}

__global__ __launch_bounds__(256) void pool_kernel(const unsigned short* __restrict__ h, const int* __restrict__ batch,
                                                   int N, float* __restrict__ out) {
    int b = blockIdx.x;
    int lo = lower_bound_i(batch, N, b);
    int hi = lower_bound_i(batch, N, b + 1);
    float acc = 0.f;
    for (int n = lo; n < hi; n++) acc += bf2f_u(h[(size_t)n * HID + threadIdx.x]);
    out[(size_t)b * HID + threadIdx.x] = acc / fmaxf((float)(hi - lo), 1.f);
}

extern "C" void kernel_launch(void* const* d_in, const int* in_sizes, int n_in,
                              void* d_out, int out_size, void* d_ws, size_t ws_size,
                              hipStream_t stream) {
    const float* x    = (const float*)d_in[0];
    const int*   ei   = (const int*)d_in[1];
    const float* ew   = (const float*)d_in[2];
    const int*   batch= (const int*)d_in[3];
    const float* W1   = (const float*)d_in[4];
    const float* as1  = (const float*)d_in[5];
    const float* ad1  = (const float*)d_in[6];
    const float* ae1  = (const float*)d_in[7];
    const float* We1  = (const float*)d_in[8];
    const float* b1   = (const float*)d_in[9];
    const float* W2   = (const float*)d_in[10];
    const float* as2  = (const float*)d_in[11];
    const float* ad2  = (const float*)d_in[12];
    const float* ae2  = (const float*)d_in[13];
    const float* We2  = (const float*)d_in[14];
    const float* b2   = (const float*)d_in[15];
    const float* ln1g = (const float*)d_in[16];
    const float* ln1b = (const float*)d_in[17];
    const float* ln2g = (const float*)d_in[18];
    const float* ln2b = (const float*)d_in[19];

    int N = in_sizes[3];
    int E = in_sizes[2];
    int FIN = in_sizes[0] / N;
    int EN = E + N;
    int B = out_size / HID;
    float* outp = (float*)d_out;
    int NB = (N + 255) / 256;

    char* ws = (char*)d_ws;
    size_t off = 0;
    auto alloc = [&](size_t bytes) { void* p = ws + off; off = (off + bytes + 255) & ~(size_t)255; return p; };
    float* sumw    = (float*)alloc(4);
    int*   deg     = (int*)  alloc((size_t)N * 4);           // zeroed region = [0, 256 + N*4)
    size_t zero_bytes = 256 + (size_t)N * 4;
    float* partials= (float*)alloc(256 * 4);
    int*   bsum    = (int*)  alloc(256 * 4);
    int*   boff    = (int*)  alloc(256 * 4);
    int*   offs    = (int*)  alloc((size_t)(N + 1) * 4);
    int*   cursor  = (int*)  alloc((size_t)N * 4);
    int*   csr_eid = (int*)  alloc((size_t)EN * 4);
    int*   csr_src = (int*)  alloc((size_t)EN * 4);
    float* csr_w   = (float*)alloc((size_t)EN * 4);
    float* asb     = (float*)alloc((size_t)N * 4 * 4);
    float* adb     = (float*)alloc((size_t)N * 4 * 4);
    float* cc      = (float*)alloc(64);
    unsigned short* w1_16 = (unsigned short*)alloc((size_t)HID * HID * 2);
    unsigned short* w2_16 = (unsigned short*)alloc((size_t)HID * HID * 2);
    unsigned short* x16   = (unsigned short*)alloc((size_t)N * HID * 2);  // x -> h1 -> h2 (reused)
    unsigned short* xp16  = (unsigned short*)alloc((size_t)N * HID * 2);
    (void)ws_size; (void)n_in;

    (void)hipMemsetAsync(d_ws, 0, zero_bytes, stream);
    sum_stage1<<<256, 256, 0, stream>>>(ew, E, partials);
    sum2_coeff_kernel<<<2, 256, 0, stream>>>(partials, sumw, We1, ae1, We2, ae2, cc, cc + 4);
    hist_kernel<<<(EN + 255) / 256, 256, 0, stream>>>(ei, E, N, deg);
    scan_reduce<<<NB, 256, 0, stream>>>(deg, N, bsum);
    scan_bsums<<<1, 256, 0, stream>>>(bsum, NB, boff);
    scan_apply<<<NB, 256, 0, stream>>>(deg, N, boff, offs, cursor);
    scatter_eid<<<(EN + 255) / 256, 256, 0, stream>>>(ei, E, N, cursor, csr_eid);
    sort_gather_kernel<<<(N + 3) / 4, 256, 0, stream>>>(offs, csr_eid, ei, ew, sumw, E, N, csr_src, csr_w);

    // weight/feature conversions
    cvt_w_both<<<512, 256, 0, stream>>>(W1, W2, w1_16, w2_16, FIN);
    cvt_pad_kernel<<<N, 256, 0, stream>>>(x, x16, FIN);

    int MB = (N + 63) / 64;
    // layer 1
    gemm_mfma<<<MB, 256, 0, stream>>>(x16, w1_16, N, as1, ad1, xp16, asb, adb);
    gat_kernel<<<(N + 3) / 4, 256, 0, stream>>>(xp16, offs, csr_src, csr_w, asb, adb, cc, b1, ln1g, ln1b, N, x16);
    // layer 2
    gemm_mfma<<<MB, 256, 0, stream>>>(x16, w2_16, N, as2, ad2, xp16, asb, adb);
    gat_kernel<<<(N + 3) / 4, 256, 0, stream>>>(xp16, offs, csr_src, csr_w, asb, adb, cc + 4, b2, ln2g, ln2b, N, x16);
    // pool
    pool_kernel<<<B, 256, 0, stream>>>(x16, batch, N, outp);
}

// Round 12
// 369.076 us; speedup vs baseline: 1.1232x; 1.0612x over previous
//
#include <hip/hip_runtime.h>
#include <math.h>

#define HID 256
#define NEG_SLOPE 0.2f
#define LN_EPS 1e-5f

typedef __attribute__((ext_vector_type(4))) float f32x4;
typedef __attribute__((ext_vector_type(8))) short bf16x8;
typedef __attribute__((address_space(3))) unsigned char lds_b;
typedef const __attribute__((address_space(1))) unsigned char glob_b;

__device__ __forceinline__ float bf2f_lo(unsigned int u) {
    union { unsigned int i; float f; } c; c.i = u << 16; return c.f;
}
__device__ __forceinline__ float bf2f_hi(unsigned int u) {
    union { unsigned int i; float f; } c; c.i = u & 0xffff0000u; return c.f;
}
__device__ __forceinline__ float bf2f_u(unsigned short u) {
    union { unsigned int i; float f; } c; c.i = ((unsigned int)u) << 16; return c.f;
}
__device__ __forceinline__ unsigned short f2bf(float f) {
    union { float f; unsigned int i; } c; c.f = f;
    unsigned int i = c.i;
    return (unsigned short)((i + 0x7fffu + ((i >> 16) & 1u)) >> 16);
}

// ---------------- deterministic sum of edge_weight ----------------
__global__ __launch_bounds__(256) void sum_stage1(const float* __restrict__ w, int n, float* __restrict__ partials) {
    __shared__ float sdata[4];
    float v = 0.f;
    for (int i = blockIdx.x * 256 + threadIdx.x; i < n; i += gridDim.x * 256) v += w[i];
    for (int o = 32; o; o >>= 1) v += __shfl_xor(v, o);
    if ((threadIdx.x & 63) == 0) sdata[threadIdx.x >> 6] = v;
    __syncthreads();
    if (threadIdx.x == 0) partials[blockIdx.x] = sdata[0] + sdata[1] + sdata[2] + sdata[3];
}

// block 0: finish edge-weight sum; block 1: per-layer edge coefficients
__global__ __launch_bounds__(256) void sum2_coeff_kernel(const float* __restrict__ partials, float* __restrict__ sumw,
                                                         const float* __restrict__ We1, const float* __restrict__ ae1,
                                                         const float* __restrict__ We2, const float* __restrict__ ae2,
                                                         float* __restrict__ c1, float* __restrict__ c2) {
    int t = threadIdx.x;
    if (blockIdx.x == 0) {
        __shared__ float sdata[4];
        float v = partials[t];
        for (int o = 32; o; o >>= 1) v += __shfl_xor(v, o);
        if ((t & 63) == 0) sdata[t >> 6] = v;
        __syncthreads();
        if (t == 0) *sumw = sdata[0] + sdata[1] + sdata[2] + sdata[3];
    } else {
        float v1 = We1[t] * ae1[t];
        float v2 = We2[t] * ae2[t];
        for (int o = 1; o < 64; o <<= 1) { v1 += __shfl_xor(v1, o); v2 += __shfl_xor(v2, o); }
        if ((t & 63) == 0) { c1[t >> 6] = v1; c2[t >> 6] = v2; }
    }
}

// ---------------- CSR build ----------------
__global__ __launch_bounds__(256) void hist_kernel(const int* __restrict__ ei, int E, int N, int* __restrict__ deg) {
    int e = blockIdx.x * 256 + threadIdx.x;
    if (e >= E + N) return;
    int d = (e < E) ? ei[E + e] : (e - E);
    atomicAdd(&deg[d], 1);
}

__global__ __launch_bounds__(256) void scan_reduce(const int* __restrict__ deg, int N, int* __restrict__ bsum) {
    __shared__ int sdata[4];
    int i = blockIdx.x * 256 + threadIdx.x;
    int v = (i < N) ? deg[i] : 0;
    for (int o = 32; o; o >>= 1) v += __shfl_xor(v, o);
    if ((threadIdx.x & 63) == 0) sdata[threadIdx.x >> 6] = v;
    __syncthreads();
    if (threadIdx.x == 0) bsum[blockIdx.x] = sdata[0] + sdata[1] + sdata[2] + sdata[3];
}

__global__ __launch_bounds__(256) void scan_bsums(const int* __restrict__ bsum, int NB, int* __restrict__ boff) {
    __shared__ int sm[256];
    int t = threadIdx.x;
    int v = (t < NB) ? bsum[t] : 0;
    sm[t] = v;
    __syncthreads();
    for (int o = 1; o < 256; o <<= 1) {
        int tv = (t >= o) ? sm[t - o] : 0;
        __syncthreads();
        sm[t] += tv;
        __syncthreads();
    }
    if (t < NB) boff[t] = sm[t] - v;
}

__global__ __launch_bounds__(256) void scan_apply(const int* __restrict__ deg, int N, const int* __restrict__ boff,
                                                  int* __restrict__ offs, int* __restrict__ cursor) {
    __shared__ int sm[256];
    int t = threadIdx.x;
    int i = blockIdx.x * 256 + t;
    int v = (i < N) ? deg[i] : 0;
    sm[t] = v;
    __syncthreads();
    for (int o = 1; o < 256; o <<= 1) {
        int tv = (t >= o) ? sm[t - o] : 0;
        __syncthreads();
        sm[t] += tv;
        __syncthreads();
    }
    if (i < N) {
        int e = boff[blockIdx.x] + sm[t] - v;
        offs[i] = e; cursor[i] = e;
        if (i == N - 1) offs[N] = boff[blockIdx.x] + sm[t];
    }
}

__global__ __launch_bounds__(256) void scatter_eid(const int* __restrict__ ei, int E, int N,
                                                   int* __restrict__ cursor, int* __restrict__ csr_eid) {
    int e = blockIdx.x * 256 + threadIdx.x;
    if (e >= E + N) return;
    int d = (e < E) ? ei[E + e] : (e - E);
    int pos = atomicAdd(&cursor[d], 1);
    csr_eid[pos] = e;
}

// Deterministic order restore + CSR payload gather, fused (wave-per-node rank sort).
__global__ __launch_bounds__(256) void sort_gather_kernel(const int* __restrict__ offs, int* __restrict__ eid,
                                                          const int* __restrict__ ei, const float* __restrict__ ew,
                                                          const float* __restrict__ sumw, int E, int N,
                                                          int* __restrict__ csr_src, float* __restrict__ csr_w) {
    int lane = threadIdx.x & 63;
    int n = (blockIdx.x << 2) + (threadIdx.x >> 6);
    if (n >= N) return;
    int s0 = offs[n];
    int d = offs[n + 1] - s0;
    if (d <= 0) return;
    if (d <= 64) {
        int key = (lane < d) ? eid[s0 + lane] : 0x7fffffff;
        int rank = 0;
        for (int j = 0; j < d; j++) {
            int kj = __shfl(key, j);
            rank += (kj < key) ? 1 : 0;
        }
        if (lane < d) {
            int s; float wv;
            if (key < E) { s = ei[key]; wv = ew[key]; }
            else         { s = key - E; wv = *sumw / (float)E; }
            csr_src[s0 + rank] = s;
            csr_w[s0 + rank] = wv;
        }
    } else {
        if (lane == 0) {
            for (int i = s0 + 1; i < s0 + d; i++) {
                int ke = eid[i];
                int j = i - 1;
                while (j >= s0 && eid[j] > ke) { eid[j + 1] = eid[j]; j--; }
                eid[j + 1] = ke;
            }
        }
        __builtin_amdgcn_wave_barrier();
        for (int i = lane; i < d; i += 64) {
            int e = eid[s0 + i];
            int s; float wv;
            if (e < E) { s = ei[e]; wv = ew[e]; }
            else       { s = e - E; wv = *sumw / (float)E; }
            csr_src[s0 + i] = s;
            csr_w[s0 + i] = wv;
        }
    }
}

// ---------------- x: fp32 -> bf16 row-major, zero-pad to 256 cols ----------------
__global__ __launch_bounds__(256) void cvt_pad_kernel(const float* __restrict__ in, unsigned short* __restrict__ out, int K) {
    int r = blockIdx.x, t = threadIdx.x;
    out[(size_t)r * 256 + t] = (t < K) ? f2bf(in[(size_t)r * K + t]) : (unsigned short)0;
}

// ---------------- both W: fp32 [256][K] -> bf16 pre-SWIZZLED LDS image, zero-pad K->256 ----------------
// Per ks (16KB): byte = j*4096 + ((col<<4) ^ (j<<4)) + e*2
__global__ __launch_bounds__(256) void cvt_w_both(const float* __restrict__ W1, const float* __restrict__ W2,
                                                  unsigned short* __restrict__ o1, unsigned short* __restrict__ o2,
                                                  int K1) {
    int b = blockIdx.x, k = threadIdx.x;
    const float* in = (b < 256) ? W1 : W2;
    unsigned short* out = (b < 256) ? o1 : o2;
    int K = (b < 256) ? K1 : 256;
    int col = b & 255;
    float v = (k < K) ? in[(size_t)col * K + k] : 0.f;
    int ks = k >> 5, j = (k >> 3) & 3, e = k & 7;
    out[ks * 8192 + j * 2048 + ((((col << 4) ^ (j << 4))) >> 1) + e] = f2bf(v);
}

// ---------------- bf16 MFMA GEMM (K=256), BM=32: A read direct from global, B via linear DMA ----------------
// 4 waves; wave w owns cols [w*64, +64) == head w. LDS = 16 KB (B tile only).
__global__ __launch_bounds__(256) void gemm_mfma(
    const unsigned short* __restrict__ A16, const unsigned short* __restrict__ Bt16, int M,
    const float* __restrict__ asf, const float* __restrict__ adf,
    unsigned short* __restrict__ C16, float* __restrict__ as_out, float* __restrict__ ad_out)
{
    __shared__ __align__(16) unsigned short Bsl[4 * 256 * 8]; // 16 KB
    int t = threadIdx.x;
    int lane = t & 63, w = t >> 6;
    int row0 = blockIdx.x << 5;
    int kg = lane >> 4, fr = lane & 15;

    // A fragment pointers (rows clamped; garbage rows discarded by write guards)
    int ar0 = row0 + fr;      if (ar0 >= M) ar0 = 0;
    int ar1 = row0 + 16 + fr; if (ar1 >= M) ar1 = 0;
    const unsigned short* ap0 = A16 + (size_t)ar0 * 256 + (kg << 3);
    const unsigned short* ap1 = A16 + (size_t)ar1 * 256 + (kg << 3);

    f32x4 acc[2][4];
#pragma unroll
    for (int i = 0; i < 2; i++)
#pragma unroll
        for (int j = 0; j < 4; j++) acc[i][j] = (f32x4){0.f, 0.f, 0.f, 0.f};

    for (int ks = 0; ks < 8; ks++) {
        // B tile: pre-swizzled file -> pure linear DMA, no VGPR round trip
#pragma unroll
        for (int j = 0; j < 4; j++) {
            __builtin_amdgcn_global_load_lds(
                (glob_b*)(Bt16 + (size_t)ks * 8192 + j * 2048 + t * 8),
                (lds_b*)((char*)Bsl + j * 4096 + t * 16),
                16, 0, 0);
        }
        bf16x8 a0 = *(const bf16x8*)(ap0 + (ks << 5));
        bf16x8 a1 = *(const bf16x8*)(ap1 + (ks << 5));
        __syncthreads();
#pragma unroll
        for (int nf = 0; nf < 4; nf++) {
            int col = (w << 6) + (nf << 4) + fr;
            bf16x8 bv = *(const bf16x8*)((const char*)Bsl + (kg << 12) + (((col << 4)) ^ (kg << 4)));
            acc[0][nf] = __builtin_amdgcn_mfma_f32_16x16x32_bf16(a0, bv, acc[0][nf], 0, 0, 0);
            acc[1][nf] = __builtin_amdgcn_mfma_f32_16x16x32_bf16(a1, bv, acc[1][nf], 0, 0, 0);
        }
        __syncthreads();
    }

    // C write (bf16); C/D frag: col = fr, row = kg*4 + j (+ mf*16)
#pragma unroll
    for (int mf = 0; mf < 2; mf++)
#pragma unroll
        for (int j = 0; j < 4; j++) {
            int gr = row0 + mf * 16 + kg * 4 + j;
            if (gr < M) {
#pragma unroll
                for (int nf = 0; nf < 4; nf++)
                    C16[(size_t)gr * 256 + (w << 6) + (nf << 4) + fr] = f2bf(acc[mf][nf][j]);
            }
        }
    // alpha epilogue: wave w == head w; exact per-row dots
    float asv[4], adv[4];
#pragma unroll
    for (int nf = 0; nf < 4; nf++) {
        int col = (w << 6) + (nf << 4) + fr;
        asv[nf] = asf[col]; adv[nf] = adf[col];
    }
#pragma unroll
    for (int mf = 0; mf < 2; mf++)
#pragma unroll
        for (int j = 0; j < 4; j++) {
            float ps = acc[mf][0][j] * asv[0] + acc[mf][1][j] * asv[1] + acc[mf][2][j] * asv[2] + acc[mf][3][j] * asv[3];
            float pd = acc[mf][0][j] * adv[0] + acc[mf][1][j] * adv[1] + acc[mf][2][j] * adv[2] + acc[mf][3][j] * adv[3];
#pragma unroll
            for (int o = 1; o < 16; o <<= 1) { ps += __shfl_xor(ps, o); pd += __shfl_xor(pd, o); }
            if (fr == 0) {
                int gr = row0 + mf * 16 + kg * 4 + j;
                if (gr < M) {
                    as_out[gr * 4 + w] = ps;
                    ad_out[gr * 4 + w] = pd;
                }
            }
        }
}

// ---------------- fused GAT + bias + LN + ELU -> bf16 out (round-9 gather shape) ----------------
#define ACC8(u, q) do { \
    acc0 += (q) * bf2f_lo((u).x); acc1 += (q) * bf2f_hi((u).x); \
    acc2 += (q) * bf2f_lo((u).y); acc3 += (q) * bf2f_hi((u).y); \
    acc4 += (q) * bf2f_lo((u).z); acc5 += (q) * bf2f_hi((u).z); \
    acc6 += (q) * bf2f_lo((u).w); acc7 += (q) * bf2f_hi((u).w); } while (0)

__global__ __launch_bounds__(256) void gat_kernel(
    const unsigned short* __restrict__ xp16, const int* __restrict__ offs,
    const int* __restrict__ csr_src, const float* __restrict__ csr_w,
    const float* __restrict__ as_, const float* __restrict__ ad_,
    const float* __restrict__ cvec, const float* __restrict__ bias,
    const float* __restrict__ ln_g, const float* __restrict__ ln_b,
    int N, unsigned short* __restrict__ out16) {
    __shared__ float p_lds[4][256];
    __shared__ int   s_lds[4][64];
    int lane = threadIdx.x & 63;
    int wid = threadIdx.x >> 6;
    int n = (blockIdx.x << 2) + wid;
    if (n >= N) return;
    int start = offs[n], end = offs[n + 1];
    int e0 = lane >> 5;
    int colb = lane & 31;
    int hq2 = colb >> 3;
    const unsigned short* xbase = xp16 + (size_t)colb * 8;
    float4 adv = *(const float4*)(ad_ + (size_t)n * 4);
    float c0 = cvec[0], c1 = cvec[1], c2 = cvec[2], c3 = cvec[3];
    float m = -INFINITY, dn = 0.f;
    float acc0 = 0, acc1 = 0, acc2 = 0, acc3 = 0, acc4 = 0, acc5 = 0, acc6 = 0, acc7 = 0;

    for (int base = start; base < end; base += 64) {
        int idx = base + lane;
        bool act = idx < end;
        int s = act ? csr_src[idx] : 0;
        float w = act ? csr_w[idx] : 0.f;
        float4 av = *(const float4*)(as_ + (size_t)s * 4);
        float l0 = av.x + adv.x + w * c0; l0 = l0 >= 0.f ? l0 : NEG_SLOPE * l0;
        float l1 = av.y + adv.y + w * c1; l1 = l1 >= 0.f ? l1 : NEG_SLOPE * l1;
        float l2 = av.z + adv.z + w * c2; l2 = l2 >= 0.f ? l2 : NEG_SLOPE * l2;
        float l3 = av.w + adv.w + w * c3; l3 = l3 >= 0.f ? l3 : NEG_SLOPE * l3;
        float lm = fmaxf(fmaxf(l0, l1), fmaxf(l2, l3));
        if (!act) lm = -INFINITY;
        for (int o = 32; o; o >>= 1) lm = fmaxf(lm, __shfl_xor(lm, o));
        float nm = fmaxf(m, lm);
        float sc = __expf(m - nm);
        m = nm;
        dn *= sc;
        acc0 *= sc; acc1 *= sc; acc2 *= sc; acc3 *= sc;
        acc4 *= sc; acc5 *= sc; acc6 *= sc; acc7 *= sc;
        float p0 = act ? __expf(l0 - m) : 0.f;
        float p1 = act ? __expf(l1 - m) : 0.f;
        float p2 = act ? __expf(l2 - m) : 0.f;
        float p3 = act ? __expf(l3 - m) : 0.f;
        float4 pv = { p0, p1, p2, p3 };
        *(float4*)&p_lds[wid][lane << 2] = pv;
        s_lds[wid][lane] = s;
        int cnt = end - base; if (cnt > 64) cnt = 64;
        int k = 0;
        for (; k + 8 <= cnt; k += 8) {
            int i0 = k + e0, i1 = k + 2 + e0, i2 = k + 4 + e0, i3 = k + 6 + e0;
            int s0 = s_lds[wid][i0], s1 = s_lds[wid][i1], s2 = s_lds[wid][i2], s3 = s_lds[wid][i3];
            uint4 u0 = *(const uint4*)(xbase + (size_t)s0 * 256);
            uint4 u1 = *(const uint4*)(xbase + (size_t)s1 * 256);
            uint4 u2 = *(const uint4*)(xbase + (size_t)s2 * 256);
            uint4 u3 = *(const uint4*)(xbase + (size_t)s3 * 256);
            float q0 = p_lds[wid][(i0 << 2) + hq2];
            float q1 = p_lds[wid][(i1 << 2) + hq2];
            float q2 = p_lds[wid][(i2 << 2) + hq2];
            float q3 = p_lds[wid][(i3 << 2) + hq2];
            dn += q0 + q1 + q2 + q3;
            ACC8(u0, q0); ACC8(u1, q1); ACC8(u2, q2); ACC8(u3, q3);
        }
        for (; k < cnt; k += 2) {
            int i = k + e0;
            bool v = i < cnt;
            int si = s_lds[wid][v ? i : 0];
            float qi = v ? p_lds[wid][(i << 2) + hq2] : 0.f;
            uint4 u = *(const uint4*)(xbase + (size_t)si * 256);
            dn += qi;
            ACC8(u, qi);
        }
    }
    acc0 += __shfl_xor(acc0, 32); acc1 += __shfl_xor(acc1, 32);
    acc2 += __shfl_xor(acc2, 32); acc3 += __shfl_xor(acc3, 32);
    acc4 += __shfl_xor(acc4, 32); acc5 += __shfl_xor(acc5, 32);
    acc6 += __shfl_xor(acc6, 32); acc7 += __shfl_xor(acc7, 32);
    dn += __shfl_xor(dn, 32);
    float inv = 1.f / dn;
    int cb8 = colb << 3;
    float4 bA = *(const float4*)(bias + cb8);
    float4 bB = *(const float4*)(bias + cb8 + 4);
    float o0 = acc0 * inv + bA.x, o1 = acc1 * inv + bA.y, o2 = acc2 * inv + bA.z, o3 = acc3 * inv + bA.w;
    float o4 = acc4 * inv + bB.x, o5 = acc5 * inv + bB.y, o6 = acc6 * inv + bB.z, o7 = acc7 * inv + bB.w;
    float part = ((o0 + o1) + (o2 + o3)) + ((o4 + o5) + (o6 + o7));
    for (int o = 16; o; o >>= 1) part += __shfl_xor(part, o);
    float mu = part * (1.f / 256.f);
    float d0 = o0 - mu, d1 = o1 - mu, d2 = o2 - mu, d3 = o3 - mu;
    float d4 = o4 - mu, d5 = o5 - mu, d6 = o6 - mu, d7 = o7 - mu;
    float vpart = ((d0 * d0 + d1 * d1) + (d2 * d2 + d3 * d3)) + ((d4 * d4 + d5 * d5) + (d6 * d6 + d7 * d7));
    for (int o = 16; o; o >>= 1) vpart += __shfl_xor(vpart, o);
    float rstd = rsqrtf(vpart * (1.f / 256.f) + LN_EPS);
    float4 gA = *(const float4*)(ln_g + cb8), gB = *(const float4*)(ln_g + cb8 + 4);
    float4 eA = *(const float4*)(ln_b + cb8), eB = *(const float4*)(ln_b + cb8 + 4);
    float y0 = d0 * rstd * gA.x + eA.x; y0 = y0 > 0.f ? y0 : __expf(y0) - 1.f;
    float y1 = d1 * rstd * gA.y + eA.y; y1 = y1 > 0.f ? y1 : __expf(y1) - 1.f;
    float y2 = d2 * rstd * gA.z + eA.z; y2 = y2 > 0.f ? y2 : __expf(y2) - 1.f;
    float y3 = d3 * rstd * gA.w + eA.w; y3 = y3 > 0.f ? y3 : __expf(y3) - 1.f;
    float y4 = d4 * rstd * gB.x + eB.x; y4 = y4 > 0.f ? y4 : __expf(y4) - 1.f;
    float y5 = d5 * rstd * gB.y + eB.y; y5 = y5 > 0.f ? y5 : __expf(y5) - 1.f;
    float y6 = d6 * rstd * gB.z + eB.z; y6 = y6 > 0.f ? y6 : __expf(y6) - 1.f;
    float y7 = d7 * rstd * gB.w + eB.w; y7 = y7 > 0.f ? y7 : __expf(y7) - 1.f;
    if (lane < 32) {
        uint4 ov;
        ov.x = ((unsigned int)f2bf(y1) << 16) | f2bf(y0);
        ov.y = ((unsigned int)f2bf(y3) << 16) | f2bf(y2);
        ov.z = ((unsigned int)f2bf(y5) << 16) | f2bf(y4);
        ov.w = ((unsigned int)f2bf(y7) << 16) | f2bf(y6);
        *(uint4*)(out16 + (size_t)n * HID + cb8) = ov;
    }
}

// ---------------- batch mean pool (bf16 input), 4-way unrolled for load ILP ----------------
__device__ __forceinline__ int lower_bound_i(const int* a, int n, int key) {
    int lo = 0, hi = n;
    while (lo < hi) { int mid = (lo + hi) >> 1; if (a[mid] < key) lo = mid + 1; else hi = mid; }
    return lo;
}

__global__ __launch_bounds__(256) void pool_kernel(const unsigned short* __restrict__ h, const int* __restrict__ batch,
                                                   int N, float* __restrict__ out) {
    int b = blockIdx.x;
    int lo = lower_bound_i(batch, N, b);
    int hi = lower_bound_i(batch, N, b + 1);
    float a0 = 0.f, a1 = 0.f, a2 = 0.f, a3 = 0.f;
    int n = lo;
    for (; n + 4 <= hi; n += 4) {
        a0 += bf2f_u(h[(size_t)(n + 0) * HID + threadIdx.x]);
        a1 += bf2f_u(h[(size_t)(n + 1) * HID + threadIdx.x]);
        a2 += bf2f_u(h[(size_t)(n + 2) * HID + threadIdx.x]);
        a3 += bf2f_u(h[(size_t)(n + 3) * HID + threadIdx.x]);
    }
    for (; n < hi; n++) a0 += bf2f_u(h[(size_t)n * HID + threadIdx.x]);
    float acc = (a0 + a1) + (a2 + a3);
    out[(size_t)b * HID + threadIdx.x] = acc / fmaxf((float)(hi - lo), 1.f);
}

extern "C" void kernel_launch(void* const* d_in, const int* in_sizes, int n_in,
                              void* d_out, int out_size, void* d_ws, size_t ws_size,
                              hipStream_t stream) {
    const float* x    = (const float*)d_in[0];
    const int*   ei   = (const int*)d_in[1];
    const float* ew   = (const float*)d_in[2];
    const int*   batch= (const int*)d_in[3];
    const float* W1   = (const float*)d_in[4];
    const float* as1  = (const float*)d_in[5];
    const float* ad1  = (const float*)d_in[6];
    const float* ae1  = (const float*)d_in[7];
    const float* We1  = (const float*)d_in[8];
    const float* b1   = (const float*)d_in[9];
    const float* W2   = (const float*)d_in[10];
    const float* as2  = (const float*)d_in[11];
    const float* ad2  = (const float*)d_in[12];
    const float* ae2  = (const float*)d_in[13];
    const float* We2  = (const float*)d_in[14];
    const float* b2   = (const float*)d_in[15];
    const float* ln1g = (const float*)d_in[16];
    const float* ln1b = (const float*)d_in[17];
    const float* ln2g = (const float*)d_in[18];
    const float* ln2b = (const float*)d_in[19];

    int N = in_sizes[3];
    int E = in_sizes[2];
    int FIN = in_sizes[0] / N;
    int EN = E + N;
    int B = out_size / HID;
    float* outp = (float*)d_out;
    int NB = (N + 255) / 256;

    char* ws = (char*)d_ws;
    size_t off = 0;
    auto alloc = [&](size_t bytes) { void* p = ws + off; off = (off + bytes + 255) & ~(size_t)255; return p; };
    float* sumw    = (float*)alloc(4);
    int*   deg     = (int*)  alloc((size_t)N * 4);           // zeroed region = [0, 256 + N*4)
    size_t zero_bytes = 256 + (size_t)N * 4;
    float* partials= (float*)alloc(256 * 4);
    int*   bsum    = (int*)  alloc(256 * 4);
    int*   boff    = (int*)  alloc(256 * 4);
    int*   offs    = (int*)  alloc((size_t)(N + 1) * 4);
    int*   cursor  = (int*)  alloc((size_t)N * 4);
    int*   csr_eid = (int*)  alloc((size_t)EN * 4);
    int*   csr_src = (int*)  alloc((size_t)EN * 4);
    float* csr_w   = (float*)alloc((size_t)EN * 4);
    float* asb     = (float*)alloc((size_t)N * 4 * 4);
    float* adb     = (float*)alloc((size_t)N * 4 * 4);
    float* cc      = (float*)alloc(64);
    unsigned short* w1_16 = (unsigned short*)alloc((size_t)HID * HID * 2);
    unsigned short* w2_16 = (unsigned short*)alloc((size_t)HID * HID * 2);
    unsigned short* x16   = (unsigned short*)alloc((size_t)N * HID * 2);  // x -> h1 -> h2 (reused)
    unsigned short* xp16  = (unsigned short*)alloc((size_t)N * HID * 2);
    (void)ws_size; (void)n_in;

    (void)hipMemsetAsync(d_ws, 0, zero_bytes, stream);
    sum_stage1<<<256, 256, 0, stream>>>(ew, E, partials);
    sum2_coeff_kernel<<<2, 256, 0, stream>>>(partials, sumw, We1, ae1, We2, ae2, cc, cc + 4);
    hist_kernel<<<(EN + 255) / 256, 256, 0, stream>>>(ei, E, N, deg);
    scan_reduce<<<NB, 256, 0, stream>>>(deg, N, bsum);
    scan_bsums<<<1, 256, 0, stream>>>(bsum, NB, boff);
    scan_apply<<<NB, 256, 0, stream>>>(deg, N, boff, offs, cursor);
    scatter_eid<<<(EN + 255) / 256, 256, 0, stream>>>(ei, E, N, cursor, csr_eid);
    sort_gather_kernel<<<(N + 3) / 4, 256, 0, stream>>>(offs, csr_eid, ei, ew, sumw, E, N, csr_src, csr_w);

    // weight/feature conversions
    cvt_w_both<<<512, 256, 0, stream>>>(W1, W2, w1_16, w2_16, FIN);
    cvt_pad_kernel<<<N, 256, 0, stream>>>(x, x16, FIN);

    int MB = (N + 31) / 32;
    // layer 1
    gemm_mfma<<<MB, 256, 0, stream>>>(x16, w1_16, N, as1, ad1, xp16, asb, adb);
    gat_kernel<<<(N + 3) / 4, 256, 0, stream>>>(xp16, offs, csr_src, csr_w, asb, adb, cc, b1, ln1g, ln1b, N, x16);
    // layer 2
    gemm_mfma<<<MB, 256, 0, stream>>>(x16, w2_16, N, as2, ad2, xp16, asb, adb);
    gat_kernel<<<(N + 3) / 4, 256, 0, stream>>>(xp16, offs, csr_src, csr_w, asb, adb, cc + 4, b2, ln2g, ln2b, N, x16);
    // pool
    pool_kernel<<<B, 256, 0, stream>>>(x16, batch, N, outp);
}

// Round 13
// 352.441 us; speedup vs baseline: 1.1762x; 1.0472x over previous
//
#include <hip/hip_runtime.h>
#include <math.h>

#define HID 256
#define NEG_SLOPE 0.2f
#define LN_EPS 1e-5f

typedef __attribute__((ext_vector_type(4))) float f32x4;
typedef __attribute__((ext_vector_type(8))) short bf16x8;
typedef __attribute__((address_space(3))) unsigned char lds_b;
typedef const __attribute__((address_space(1))) unsigned char glob_b;

__device__ __forceinline__ float bf2f_lo(unsigned int u) {
    union { unsigned int i; float f; } c; c.i = u << 16; return c.f;
}
__device__ __forceinline__ float bf2f_hi(unsigned int u) {
    union { unsigned int i; float f; } c; c.i = u & 0xffff0000u; return c.f;
}
__device__ __forceinline__ float bf2f_u(unsigned short u) {
    union { unsigned int i; float f; } c; c.i = ((unsigned int)u) << 16; return c.f;
}
__device__ __forceinline__ unsigned short f2bf(float f) {
    union { float f; unsigned int i; } c; c.f = f;
    unsigned int i = c.i;
    return (unsigned short)((i + 0x7fffu + ((i >> 16) & 1u)) >> 16);
}

// ================= merged: edge-weight sum (blocks 0..255) + degree histogram =================
__global__ __launch_bounds__(256) void k_sum_hist(const float* __restrict__ ew, int E,
                                                  const int* __restrict__ ei, int N,
                                                  float* __restrict__ partials, int* __restrict__ deg) {
    int t = threadIdx.x;
    if (blockIdx.x < 256) {
        __shared__ float sdata[4];
        float v = 0.f;
        for (int i = blockIdx.x * 256 + t; i < E; i += 65536) v += ew[i];
        for (int o = 32; o; o >>= 1) v += __shfl_xor(v, o);
        if ((t & 63) == 0) sdata[t >> 6] = v;
        __syncthreads();
        if (t == 0) partials[blockIdx.x] = sdata[0] + sdata[1] + sdata[2] + sdata[3];
    } else {
        int e = (blockIdx.x - 256) * 256 + t;
        if (e >= E + N) return;
        int d = (e < E) ? ei[E + e] : (e - E);
        atomicAdd(&deg[d], 1);
    }
}

// ================= merged: per-block degree sums (0..NB-1) + sumw finish (NB) + coeff (NB+1) =================
__global__ __launch_bounds__(256) void k_scanred_coeff(const int* __restrict__ deg, int N, int NB,
                                                       int* __restrict__ bsum,
                                                       const float* __restrict__ partials, float* __restrict__ sumw,
                                                       const float* __restrict__ We1, const float* __restrict__ ae1,
                                                       const float* __restrict__ We2, const float* __restrict__ ae2,
                                                       float* __restrict__ c1, float* __restrict__ c2) {
    int t = threadIdx.x;
    int b = blockIdx.x;
    if (b < NB) {
        __shared__ int sdata[4];
        int i = b * 256 + t;
        int v = (i < N) ? deg[i] : 0;
        for (int o = 32; o; o >>= 1) v += __shfl_xor(v, o);
        if ((t & 63) == 0) sdata[t >> 6] = v;
        __syncthreads();
        if (t == 0) bsum[b] = sdata[0] + sdata[1] + sdata[2] + sdata[3];
    } else if (b == NB) {
        __shared__ float sdata[4];
        float v = partials[t];
        for (int o = 32; o; o >>= 1) v += __shfl_xor(v, o);
        if ((t & 63) == 0) sdata[t >> 6] = v;
        __syncthreads();
        if (t == 0) *sumw = sdata[0] + sdata[1] + sdata[2] + sdata[3];
    } else {
        float v1 = We1[t] * ae1[t];
        float v2 = We2[t] * ae2[t];
        for (int o = 1; o < 64; o <<= 1) { v1 += __shfl_xor(v1, o); v2 += __shfl_xor(v2, o); }
        if ((t & 63) == 0) { c1[t >> 6] = v1; c2[t >> 6] = v2; }
    }
}

// ================= scan_apply with inline scan of block sums (replaces scan_bsums) =================
__global__ __launch_bounds__(256) void k_scan_apply(const int* __restrict__ deg, int N, int NB,
                                                    const int* __restrict__ bsum,
                                                    int* __restrict__ offs, int* __restrict__ cursor) {
    __shared__ int sm[256];
    __shared__ int sb[256];
    int t = threadIdx.x;
    int i = blockIdx.x * 256 + t;
    int v = (i < N) ? deg[i] : 0;
    int vb = (t < NB) ? bsum[t] : 0;
    sm[t] = v;
    sb[t] = vb;
    __syncthreads();
    for (int o = 1; o < 256; o <<= 1) {
        int tv = (t >= o) ? sm[t - o] : 0;
        int tb = (t >= o) ? sb[t - o] : 0;
        __syncthreads();
        sm[t] += tv;
        sb[t] += tb;
        __syncthreads();
    }
    int myb = bsum[blockIdx.x];                 // blockIdx < NB always
    int boff = sb[blockIdx.x] - myb;            // exclusive prefix of block sums
    if (i < N) {
        int e = boff + sm[t] - v;
        offs[i] = e; cursor[i] = e;
        if (i == N - 1) offs[N] = boff + sm[t];
    }
}

// ================= merged: scatter_eid + cvt_w + cvt_pad (mutually independent) =================
__global__ __launch_bounds__(256) void k_scatter_cvt(const int* __restrict__ ei, int E, int N, int NS,
                                                     int* __restrict__ cursor, int* __restrict__ csr_eid,
                                                     const float* __restrict__ W1, const float* __restrict__ W2,
                                                     unsigned short* __restrict__ o1, unsigned short* __restrict__ o2, int K1,
                                                     const float* __restrict__ x, unsigned short* __restrict__ x16, int FIN) {
    int t = threadIdx.x;
    int b = blockIdx.x;
    if (b < NS) {
        int e = b * 256 + t;
        if (e >= E + N) return;
        int d = (e < E) ? ei[E + e] : (e - E);
        int pos = atomicAdd(&cursor[d], 1);
        csr_eid[pos] = e;
    } else if (b < NS + 512) {
        int wb = b - NS;
        const float* in = (wb < 256) ? W1 : W2;
        unsigned short* out = (wb < 256) ? o1 : o2;
        int K = (wb < 256) ? K1 : 256;
        int col = wb & 255;
        float v = (t < K) ? in[(size_t)col * K + t] : 0.f;
        int ks = t >> 5, j = (t >> 3) & 3, e = t & 7;
        out[ks * 8192 + j * 2048 + ((((col << 4) ^ (j << 4))) >> 1) + e] = f2bf(v);
    } else {
        int r = b - NS - 512;
        x16[(size_t)r * 256 + t] = (t < FIN) ? f2bf(x[(size_t)r * FIN + t]) : (unsigned short)0;
    }
}

// ================= device bodies for gemm / sort_gather (shared by merged + standalone kernels) =================
__device__ __forceinline__ void gemm_dev(int bid,
    const unsigned short* __restrict__ A16, const unsigned short* __restrict__ Bt16, int M,
    const float* __restrict__ asf, const float* __restrict__ adf,
    unsigned short* __restrict__ C16, float* __restrict__ as_out, float* __restrict__ ad_out)
{
    __shared__ __align__(16) unsigned short Bsl[4 * 256 * 8]; // 16 KB
    int t = threadIdx.x;
    int lane = t & 63, w = t >> 6;
    int row0 = bid << 5;
    int kg = lane >> 4, fr = lane & 15;

    int ar0 = row0 + fr;      if (ar0 >= M) ar0 = 0;
    int ar1 = row0 + 16 + fr; if (ar1 >= M) ar1 = 0;
    const unsigned short* ap0 = A16 + (size_t)ar0 * 256 + (kg << 3);
    const unsigned short* ap1 = A16 + (size_t)ar1 * 256 + (kg << 3);

    f32x4 acc[2][4];
#pragma unroll
    for (int i = 0; i < 2; i++)
#pragma unroll
        for (int j = 0; j < 4; j++) acc[i][j] = (f32x4){0.f, 0.f, 0.f, 0.f};

    for (int ks = 0; ks < 8; ks++) {
#pragma unroll
        for (int j = 0; j < 4; j++) {
            __builtin_amdgcn_global_load_lds(
                (glob_b*)(Bt16 + (size_t)ks * 8192 + j * 2048 + t * 8),
                (lds_b*)((char*)Bsl + j * 4096 + t * 16),
                16, 0, 0);
        }
        bf16x8 a0 = *(const bf16x8*)(ap0 + (ks << 5));
        bf16x8 a1 = *(const bf16x8*)(ap1 + (ks << 5));
        __syncthreads();
#pragma unroll
        for (int nf = 0; nf < 4; nf++) {
            int col = (w << 6) + (nf << 4) + fr;
            bf16x8 bv = *(const bf16x8*)((const char*)Bsl + (kg << 12) + (((col << 4)) ^ (kg << 4)));
            acc[0][nf] = __builtin_amdgcn_mfma_f32_16x16x32_bf16(a0, bv, acc[0][nf], 0, 0, 0);
            acc[1][nf] = __builtin_amdgcn_mfma_f32_16x16x32_bf16(a1, bv, acc[1][nf], 0, 0, 0);
        }
        __syncthreads();
    }

#pragma unroll
    for (int mf = 0; mf < 2; mf++)
#pragma unroll
        for (int j = 0; j < 4; j++) {
            int gr = row0 + mf * 16 + kg * 4 + j;
            if (gr < M) {
#pragma unroll
                for (int nf = 0; nf < 4; nf++)
                    C16[(size_t)gr * 256 + (w << 6) + (nf << 4) + fr] = f2bf(acc[mf][nf][j]);
            }
        }
    float asv[4], adv[4];
#pragma unroll
    for (int nf = 0; nf < 4; nf++) {
        int col = (w << 6) + (nf << 4) + fr;
        asv[nf] = asf[col]; adv[nf] = adf[col];
    }
#pragma unroll
    for (int mf = 0; mf < 2; mf++)
#pragma unroll
        for (int j = 0; j < 4; j++) {
            float ps = acc[mf][0][j] * asv[0] + acc[mf][1][j] * asv[1] + acc[mf][2][j] * asv[2] + acc[mf][3][j] * asv[3];
            float pd = acc[mf][0][j] * adv[0] + acc[mf][1][j] * adv[1] + acc[mf][2][j] * adv[2] + acc[mf][3][j] * adv[3];
#pragma unroll
            for (int o = 1; o < 16; o <<= 1) { ps += __shfl_xor(ps, o); pd += __shfl_xor(pd, o); }
            if (fr == 0) {
                int gr = row0 + mf * 16 + kg * 4 + j;
                if (gr < M) {
                    as_out[gr * 4 + w] = ps;
                    ad_out[gr * 4 + w] = pd;
                }
            }
        }
}

__device__ __forceinline__ void sort_gather_dev(int bid, const int* __restrict__ offs, int* __restrict__ eid,
                                                const int* __restrict__ ei, const float* __restrict__ ew,
                                                const float* __restrict__ sumw, int E, int N,
                                                int* __restrict__ csr_src, float* __restrict__ csr_w) {
    int lane = threadIdx.x & 63;
    int n = (bid << 2) + (threadIdx.x >> 6);
    if (n >= N) return;
    int s0 = offs[n];
    int d = offs[n + 1] - s0;
    if (d <= 0) return;
    if (d <= 64) {
        int key = (lane < d) ? eid[s0 + lane] : 0x7fffffff;
        int rank = 0;
        for (int j = 0; j < d; j++) {
            int kj = __shfl(key, j);
            rank += (kj < key) ? 1 : 0;
        }
        if (lane < d) {
            int s; float wv;
            if (key < E) { s = ei[key]; wv = ew[key]; }
            else         { s = key - E; wv = *sumw / (float)E; }
            csr_src[s0 + rank] = s;
            csr_w[s0 + rank] = wv;
        }
    } else {
        if (lane == 0) {
            for (int i = s0 + 1; i < s0 + d; i++) {
                int ke = eid[i];
                int j = i - 1;
                while (j >= s0 && eid[j] > ke) { eid[j + 1] = eid[j]; j--; }
                eid[j + 1] = ke;
            }
        }
        __builtin_amdgcn_wave_barrier();
        for (int i = lane; i < d; i += 64) {
            int e = eid[s0 + i];
            int s; float wv;
            if (e < E) { s = ei[e]; wv = ew[e]; }
            else       { s = e - E; wv = *sumw / (float)E; }
            csr_src[s0 + i] = s;
            csr_w[s0 + i] = wv;
        }
    }
}

// ================= merged: gemm layer-1 (blocks [0,MB)) + sort_gather (blocks [MB,...)) =================
__global__ __launch_bounds__(256) void k_gemm_sort(int MB,
    const unsigned short* __restrict__ A16, const unsigned short* __restrict__ Bt16, int M,
    const float* __restrict__ asf, const float* __restrict__ adf,
    unsigned short* __restrict__ C16, float* __restrict__ as_out, float* __restrict__ ad_out,
    const int* __restrict__ offs, int* __restrict__ eid,
    const int* __restrict__ ei, const float* __restrict__ ew,
    const float* __restrict__ sumw, int E,
    int* __restrict__ csr_src, float* __restrict__ csr_w) {
    if ((int)blockIdx.x < MB)
        gemm_dev(blockIdx.x, A16, Bt16, M, asf, adf, C16, as_out, ad_out);
    else
        sort_gather_dev(blockIdx.x - MB, offs, eid, ei, ew, sumw, E, M, csr_src, csr_w);
}

// ================= standalone gemm (layer 2) =================
__global__ __launch_bounds__(256) void gemm_mfma(
    const unsigned short* __restrict__ A16, const unsigned short* __restrict__ Bt16, int M,
    const float* __restrict__ asf, const float* __restrict__ adf,
    unsigned short* __restrict__ C16, float* __restrict__ as_out, float* __restrict__ ad_out) {
    gemm_dev(blockIdx.x, A16, Bt16, M, asf, adf, C16, as_out, ad_out);
}

// ================= fused GAT + bias + LN + ELU -> bf16 out =================
#define ACC8(u, q) do { \
    acc0 += (q) * bf2f_lo((u).x); acc1 += (q) * bf2f_hi((u).x); \
    acc2 += (q) * bf2f_lo((u).y); acc3 += (q) * bf2f_hi((u).y); \
    acc4 += (q) * bf2f_lo((u).z); acc5 += (q) * bf2f_hi((u).z); \
    acc6 += (q) * bf2f_lo((u).w); acc7 += (q) * bf2f_hi((u).w); } while (0)

__global__ __launch_bounds__(256) void gat_kernel(
    const unsigned short* __restrict__ xp16, const int* __restrict__ offs,
    const int* __restrict__ csr_src, const float* __restrict__ csr_w,
    const float* __restrict__ as_, const float* __restrict__ ad_,
    const float* __restrict__ cvec, const float* __restrict__ bias,
    const float* __restrict__ ln_g, const float* __restrict__ ln_b,
    int N, unsigned short* __restrict__ out16) {
    __shared__ float p_lds[4][256];
    __shared__ int   s_lds[4][64];
    int lane = threadIdx.x & 63;
    int wid = threadIdx.x >> 6;
    int n = (blockIdx.x << 2) + wid;
    if (n >= N) return;
    int start = offs[n], end = offs[n + 1];
    int e0 = lane >> 5;
    int colb = lane & 31;
    int hq2 = colb >> 3;
    const unsigned short* xbase = xp16 + (size_t)colb * 8;
    float4 adv = *(const float4*)(ad_ + (size_t)n * 4);
    float c0 = cvec[0], c1 = cvec[1], c2 = cvec[2], c3 = cvec[3];
    float m = -INFINITY, dn = 0.f;
    float acc0 = 0, acc1 = 0, acc2 = 0, acc3 = 0, acc4 = 0, acc5 = 0, acc6 = 0, acc7 = 0;

    for (int base = start; base < end; base += 64) {
        int idx = base + lane;
        bool act = idx < end;
        int s = act ? csr_src[idx] : 0;
        float w = act ? csr_w[idx] : 0.f;
        float4 av = *(const float4*)(as_ + (size_t)s * 4);
        float l0 = av.x + adv.x + w * c0; l0 = l0 >= 0.f ? l0 : NEG_SLOPE * l0;
        float l1 = av.y + adv.y + w * c1; l1 = l1 >= 0.f ? l1 : NEG_SLOPE * l1;
        float l2 = av.z + adv.z + w * c2; l2 = l2 >= 0.f ? l2 : NEG_SLOPE * l2;
        float l3 = av.w + adv.w + w * c3; l3 = l3 >= 0.f ? l3 : NEG_SLOPE * l3;
        float lm = fmaxf(fmaxf(l0, l1), fmaxf(l2, l3));
        if (!act) lm = -INFINITY;
        for (int o = 32; o; o >>= 1) lm = fmaxf(lm, __shfl_xor(lm, o));
        float nm = fmaxf(m, lm);
        float sc = __expf(m - nm);
        m = nm;
        dn *= sc;
        acc0 *= sc; acc1 *= sc; acc2 *= sc; acc3 *= sc;
        acc4 *= sc; acc5 *= sc; acc6 *= sc; acc7 *= sc;
        float p0 = act ? __expf(l0 - m) : 0.f;
        float p1 = act ? __expf(l1 - m) : 0.f;
        float p2 = act ? __expf(l2 - m) : 0.f;
        float p3 = act ? __expf(l3 - m) : 0.f;
        float4 pv = { p0, p1, p2, p3 };
        *(float4*)&p_lds[wid][lane << 2] = pv;
        s_lds[wid][lane] = s;
        int cnt = end - base; if (cnt > 64) cnt = 64;
        int k = 0;
        for (; k + 8 <= cnt; k += 8) {
            int i0 = k + e0, i1 = k + 2 + e0, i2 = k + 4 + e0, i3 = k + 6 + e0;
            int s0 = s_lds[wid][i0], s1 = s_lds[wid][i1], s2 = s_lds[wid][i2], s3 = s_lds[wid][i3];
            uint4 u0 = *(const uint4*)(xbase + (size_t)s0 * 256);
            uint4 u1 = *(const uint4*)(xbase + (size_t)s1 * 256);
            uint4 u2 = *(const uint4*)(xbase + (size_t)s2 * 256);
            uint4 u3 = *(const uint4*)(xbase + (size_t)s3 * 256);
            float q0 = p_lds[wid][(i0 << 2) + hq2];
            float q1 = p_lds[wid][(i1 << 2) + hq2];
            float q2 = p_lds[wid][(i2 << 2) + hq2];
            float q3 = p_lds[wid][(i3 << 2) + hq2];
            dn += q0 + q1 + q2 + q3;
            ACC8(u0, q0); ACC8(u1, q1); ACC8(u2, q2); ACC8(u3, q3);
        }
        for (; k < cnt; k += 2) {
            int i = k + e0;
            bool v = i < cnt;
            int si = s_lds[wid][v ? i : 0];
            float qi = v ? p_lds[wid][(i << 2) + hq2] : 0.f;
            uint4 u = *(const uint4*)(xbase + (size_t)si * 256);
            dn += qi;
            ACC8(u, qi);
        }
    }
    acc0 += __shfl_xor(acc0, 32); acc1 += __shfl_xor(acc1, 32);
    acc2 += __shfl_xor(acc2, 32); acc3 += __shfl_xor(acc3, 32);
    acc4 += __shfl_xor(acc4, 32); acc5 += __shfl_xor(acc5, 32);
    acc6 += __shfl_xor(acc6, 32); acc7 += __shfl_xor(acc7, 32);
    dn += __shfl_xor(dn, 32);
    float inv = 1.f / dn;
    int cb8 = colb << 3;
    float4 bA = *(const float4*)(bias + cb8);
    float4 bB = *(const float4*)(bias + cb8 + 4);
    float o0 = acc0 * inv + bA.x, o1 = acc1 * inv + bA.y, o2 = acc2 * inv + bA.z, o3 = acc3 * inv + bA.w;
    float o4 = acc4 * inv + bB.x, o5 = acc5 * inv + bB.y, o6 = acc6 * inv + bB.z, o7 = acc7 * inv + bB.w;
    float part = ((o0 + o1) + (o2 + o3)) + ((o4 + o5) + (o6 + o7));
    for (int o = 16; o; o >>= 1) part += __shfl_xor(part, o);
    float mu = part * (1.f / 256.f);
    float d0 = o0 - mu, d1 = o1 - mu, d2 = o2 - mu, d3 = o3 - mu;
    float d4 = o4 - mu, d5 = o5 - mu, d6 = o6 - mu, d7 = o7 - mu;
    float vpart = ((d0 * d0 + d1 * d1) + (d2 * d2 + d3 * d3)) + ((d4 * d4 + d5 * d5) + (d6 * d6 + d7 * d7));
    for (int o = 16; o; o >>= 1) vpart += __shfl_xor(vpart, o);
    float rstd = rsqrtf(vpart * (1.f / 256.f) + LN_EPS);
    float4 gA = *(const float4*)(ln_g + cb8), gB = *(const float4*)(ln_g + cb8 + 4);
    float4 eA = *(const float4*)(ln_b + cb8), eB = *(const float4*)(ln_b + cb8 + 4);
    float y0 = d0 * rstd * gA.x + eA.x; y0 = y0 > 0.f ? y0 : __expf(y0) - 1.f;
    float y1 = d1 * rstd * gA.y + eA.y; y1 = y1 > 0.f ? y1 : __expf(y1) - 1.f;
    float y2 = d2 * rstd * gA.z + eA.z; y2 = y2 > 0.f ? y2 : __expf(y2) - 1.f;
    float y3 = d3 * rstd * gA.w + eA.w; y3 = y3 > 0.f ? y3 : __expf(y3) - 1.f;
    float y4 = d4 * rstd * gB.x + eB.x; y4 = y4 > 0.f ? y4 : __expf(y4) - 1.f;
    float y5 = d5 * rstd * gB.y + eB.y; y5 = y5 > 0.f ? y5 : __expf(y5) - 1.f;
    float y6 = d6 * rstd * gB.z + eB.z; y6 = y6 > 0.f ? y6 : __expf(y6) - 1.f;
    float y7 = d7 * rstd * gB.w + eB.w; y7 = y7 > 0.f ? y7 : __expf(y7) - 1.f;
    if (lane < 32) {
        uint4 ov;
        ov.x = ((unsigned int)f2bf(y1) << 16) | f2bf(y0);
        ov.y = ((unsigned int)f2bf(y3) << 16) | f2bf(y2);
        ov.z = ((unsigned int)f2bf(y5) << 16) | f2bf(y4);
        ov.w = ((unsigned int)f2bf(y7) << 16) | f2bf(y6);
        *(uint4*)(out16 + (size_t)n * HID + cb8) = ov;
    }
}

// ================= batch mean pool (bf16 input), 4-way unrolled =================
__device__ __forceinline__ int lower_bound_i(const int* a, int n, int key) {
    int lo = 0, hi = n;
    while (lo < hi) { int mid = (lo + hi) >> 1; if (a[mid] < key) lo = mid + 1; else hi = mid; }
    return lo;
}

__global__ __launch_bounds__(256) void pool_kernel(const unsigned short* __restrict__ h, const int* __restrict__ batch,
                                                   int N, float* __restrict__ out) {
    int b = blockIdx.x;
    int lo = lower_bound_i(batch, N, b);
    int hi = lower_bound_i(batch, N, b + 1);
    float a0 = 0.f, a1 = 0.f, a2 = 0.f, a3 = 0.f;
    int n = lo;
    for (; n + 4 <= hi; n += 4) {
        a0 += bf2f_u(h[(size_t)(n + 0) * HID + threadIdx.x]);
        a1 += bf2f_u(h[(size_t)(n + 1) * HID + threadIdx.x]);
        a2 += bf2f_u(h[(size_t)(n + 2) * HID + threadIdx.x]);
        a3 += bf2f_u(h[(size_t)(n + 3) * HID + threadIdx.x]);
    }
    for (; n < hi; n++) a0 += bf2f_u(h[(size_t)n * HID + threadIdx.x]);
    float acc = (a0 + a1) + (a2 + a3);
    out[(size_t)b * HID + threadIdx.x] = acc / fmaxf((float)(hi - lo), 1.f);
}

extern "C" void kernel_launch(void* const* d_in, const int* in_sizes, int n_in,
                              void* d_out, int out_size, void* d_ws, size_t ws_size,
                              hipStream_t stream) {
    const float* x    = (const float*)d_in[0];
    const int*   ei   = (const int*)d_in[1];
    const float* ew   = (const float*)d_in[2];
    const int*   batch= (const int*)d_in[3];
    const float* W1   = (const float*)d_in[4];
    const float* as1  = (const float*)d_in[5];
    const float* ad1  = (const float*)d_in[6];
    const float* ae1  = (const float*)d_in[7];
    const float* We1  = (const float*)d_in[8];
    const float* b1   = (const float*)d_in[9];
    const float* W2   = (const float*)d_in[10];
    const float* as2  = (const float*)d_in[11];
    const float* ad2  = (const float*)d_in[12];
    const float* ae2  = (const float*)d_in[13];
    const float* We2  = (const float*)d_in[14];
    const float* b2   = (const float*)d_in[15];
    const float* ln1g = (const float*)d_in[16];
    const float* ln1b = (const float*)d_in[17];
    const float* ln2g = (const float*)d_in[18];
    const float* ln2b = (const float*)d_in[19];

    int N = in_sizes[3];
    int E = in_sizes[2];
    int FIN = in_sizes[0] / N;
    int EN = E + N;
    int B = out_size / HID;
    float* outp = (float*)d_out;
    int NB = (N + 255) / 256;          // <= 256 required (N=50000 -> 196)
    int NS = (EN + 255) / 256;         // scatter blocks

    char* ws = (char*)d_ws;
    size_t off = 0;
    auto alloc = [&](size_t bytes) { void* p = ws + off; off = (off + bytes + 255) & ~(size_t)255; return p; };
    float* sumw    = (float*)alloc(4);
    int*   deg     = (int*)  alloc((size_t)N * 4);           // zeroed region = [0, 256 + N*4)
    size_t zero_bytes = 256 + (size_t)N * 4;
    float* partials= (float*)alloc(256 * 4);
    int*   bsum    = (int*)  alloc(256 * 4);
    int*   offs    = (int*)  alloc((size_t)(N + 1) * 4);
    int*   cursor  = (int*)  alloc((size_t)N * 4);
    int*   csr_eid = (int*)  alloc((size_t)EN * 4);
    int*   csr_src = (int*)  alloc((size_t)EN * 4);
    float* csr_w   = (float*)alloc((size_t)EN * 4);
    float* asb     = (float*)alloc((size_t)N * 4 * 4);
    float* adb     = (float*)alloc((size_t)N * 4 * 4);
    float* cc      = (float*)alloc(64);
    unsigned short* w1_16 = (unsigned short*)alloc((size_t)HID * HID * 2);
    unsigned short* w2_16 = (unsigned short*)alloc((size_t)HID * HID * 2);
    unsigned short* x16   = (unsigned short*)alloc((size_t)N * HID * 2);  // x -> h1 -> h2 (reused)
    unsigned short* xp16  = (unsigned short*)alloc((size_t)N * HID * 2);
    (void)ws_size; (void)n_in;

    int MB = (N + 31) / 32;

    (void)hipMemsetAsync(d_ws, 0, zero_bytes, stream);
    k_sum_hist<<<256 + NS, 256, 0, stream>>>(ew, E, ei, N, partials, deg);
    k_scanred_coeff<<<NB + 2, 256, 0, stream>>>(deg, N, NB, bsum, partials, sumw, We1, ae1, We2, ae2, cc, cc + 4);
    k_scan_apply<<<NB, 256, 0, stream>>>(deg, N, NB, bsum, offs, cursor);
    k_scatter_cvt<<<NS + 512 + N, 256, 0, stream>>>(ei, E, N, NS, cursor, csr_eid,
                                                    W1, W2, w1_16, w2_16, FIN, x, x16, FIN);
    // layer 1 gemm + sort_gather (independent work, one grid)
    k_gemm_sort<<<MB + (N + 3) / 4, 256, 0, stream>>>(MB, x16, w1_16, N, as1, ad1, xp16, asb, adb,
                                                      offs, csr_eid, ei, ew, sumw, E, csr_src, csr_w);
    gat_kernel<<<(N + 3) / 4, 256, 0, stream>>>(xp16, offs, csr_src, csr_w, asb, adb, cc, b1, ln1g, ln1b, N, x16);
    // layer 2
    gemm_mfma<<<MB, 256, 0, stream>>>(x16, w2_16, N, as2, ad2, xp16, asb, adb);
    gat_kernel<<<(N + 3) / 4, 256, 0, stream>>>(xp16, offs, csr_src, csr_w, asb, adb, cc + 4, b2, ln2g, ln2b, N, x16);
    // pool
    pool_kernel<<<B, 256, 0, stream>>>(x16, batch, N, outp);
}

// Round 14
// 351.043 us; speedup vs baseline: 1.1809x; 1.0040x over previous
//
#include <hip/hip_runtime.h>
#include <math.h>

#define HID 256
#define NEG_SLOPE 0.2f
#define LN_EPS 1e-5f

typedef __attribute__((ext_vector_type(4))) float f32x4;
typedef __attribute__((ext_vector_type(8))) short bf16x8;
typedef __attribute__((address_space(3))) unsigned char lds_b;
typedef const __attribute__((address_space(1))) unsigned char glob_b;

__device__ __forceinline__ float bf2f_lo(unsigned int u) {
    union { unsigned int i; float f; } c; c.i = u << 16; return c.f;
}
__device__ __forceinline__ float bf2f_hi(unsigned int u) {
    union { unsigned int i; float f; } c; c.i = u & 0xffff0000u; return c.f;
}
__device__ __forceinline__ float bf2f_u(unsigned short u) {
    union { unsigned int i; float f; } c; c.i = ((unsigned int)u) << 16; return c.f;
}
__device__ __forceinline__ unsigned short f2bf(float f) {
    union { float f; unsigned int i; } c; c.f = f;
    unsigned int i = c.i;
    return (unsigned short)((i + 0x7fffu + ((i >> 16) & 1u)) >> 16);
}

// ================= k_pre: ew-sum (0..255) + 4-way-ILP hist + cvt_w + cvt_pad, one grid =================
__global__ __launch_bounds__(256) void k_pre(const float* __restrict__ ew, int E,
                                             const int* __restrict__ ei, int N, int EN, int NH,
                                             float* __restrict__ partials, int* __restrict__ deg,
                                             const float* __restrict__ W1, const float* __restrict__ W2,
                                             unsigned short* __restrict__ o1, unsigned short* __restrict__ o2, int K1,
                                             const float* __restrict__ x, unsigned short* __restrict__ x16, int FIN) {
    int t = threadIdx.x;
    int b = blockIdx.x;
    if (b < 256) {
        __shared__ float sdata[4];
        float v = 0.f;
        for (int i = b * 256 + t; i < E; i += 65536) v += ew[i];
        for (int o = 32; o; o >>= 1) v += __shfl_xor(v, o);
        if ((t & 63) == 0) sdata[t >> 6] = v;
        __syncthreads();
        if (t == 0) partials[b] = sdata[0] + sdata[1] + sdata[2] + sdata[3];
    } else if (b < 256 + NH) {
        // histogram, 4 independent edges per thread
        int i = (b - 256) * 1024 + t;
        int e0 = i, e1 = i + 256, e2 = i + 512, e3 = i + 768;
        bool v0 = e0 < EN, v1 = e1 < EN, v2 = e2 < EN, v3 = e3 < EN;
        int d0 = v0 ? ((e0 < E) ? ei[E + e0] : e0 - E) : 0;
        int d1 = v1 ? ((e1 < E) ? ei[E + e1] : e1 - E) : 0;
        int d2 = v2 ? ((e2 < E) ? ei[E + e2] : e2 - E) : 0;
        int d3 = v3 ? ((e3 < E) ? ei[E + e3] : e3 - E) : 0;
        if (v0) atomicAdd(&deg[d0], 1);
        if (v1) atomicAdd(&deg[d1], 1);
        if (v2) atomicAdd(&deg[d2], 1);
        if (v3) atomicAdd(&deg[d3], 1);
    } else if (b < 256 + NH + 512) {
        int wb = b - 256 - NH;
        const float* in = (wb < 256) ? W1 : W2;
        unsigned short* out = (wb < 256) ? o1 : o2;
        int K = (wb < 256) ? K1 : 256;
        int col = wb & 255;
        float v = (t < K) ? in[(size_t)col * K + t] : 0.f;
        int ks = t >> 5, j = (t >> 3) & 3, e = t & 7;
        out[ks * 8192 + j * 2048 + ((((col << 4) ^ (j << 4))) >> 1) + e] = f2bf(v);
    } else {
        int r = b - 256 - NH - 512;
        x16[(size_t)r * 256 + t] = (t < FIN) ? f2bf(x[(size_t)r * FIN + t]) : (unsigned short)0;
    }
}

// ================= merged: per-block degree sums (0..NB-1) + sumw finish (NB) + coeff (NB+1) =================
__global__ __launch_bounds__(256) void k_scanred_coeff(const int* __restrict__ deg, int N, int NB,
                                                       int* __restrict__ bsum,
                                                       const float* __restrict__ partials, float* __restrict__ sumw,
                                                       const float* __restrict__ We1, const float* __restrict__ ae1,
                                                       const float* __restrict__ We2, const float* __restrict__ ae2,
                                                       float* __restrict__ c1, float* __restrict__ c2) {
    int t = threadIdx.x;
    int b = blockIdx.x;
    if (b < NB) {
        __shared__ int sdata[4];
        int i = b * 256 + t;
        int v = (i < N) ? deg[i] : 0;
        for (int o = 32; o; o >>= 1) v += __shfl_xor(v, o);
        if ((t & 63) == 0) sdata[t >> 6] = v;
        __syncthreads();
        if (t == 0) bsum[b] = sdata[0] + sdata[1] + sdata[2] + sdata[3];
    } else if (b == NB) {
        __shared__ float sdata[4];
        float v = partials[t];
        for (int o = 32; o; o >>= 1) v += __shfl_xor(v, o);
        if ((t & 63) == 0) sdata[t >> 6] = v;
        __syncthreads();
        if (t == 0) *sumw = sdata[0] + sdata[1] + sdata[2] + sdata[3];
    } else {
        float v1 = We1[t] * ae1[t];
        float v2 = We2[t] * ae2[t];
        for (int o = 1; o < 64; o <<= 1) { v1 += __shfl_xor(v1, o); v2 += __shfl_xor(v2, o); }
        if ((t & 63) == 0) { c1[t >> 6] = v1; c2[t >> 6] = v2; }
    }
}

// ================= scan_apply with inline scan of block sums =================
__global__ __launch_bounds__(256) void k_scan_apply(const int* __restrict__ deg, int N, int NB,
                                                    const int* __restrict__ bsum,
                                                    int* __restrict__ offs, int* __restrict__ cursor) {
    __shared__ int sm[256];
    __shared__ int sb[256];
    int t = threadIdx.x;
    int i = blockIdx.x * 256 + t;
    int v = (i < N) ? deg[i] : 0;
    int vb = (t < NB) ? bsum[t] : 0;
    sm[t] = v;
    sb[t] = vb;
    __syncthreads();
    for (int o = 1; o < 256; o <<= 1) {
        int tv = (t >= o) ? sm[t - o] : 0;
        int tb = (t >= o) ? sb[t - o] : 0;
        __syncthreads();
        sm[t] += tv;
        sb[t] += tb;
        __syncthreads();
    }
    int myb = bsum[blockIdx.x];
    int boff = sb[blockIdx.x] - myb;
    if (i < N) {
        int e = boff + sm[t] - v;
        offs[i] = e; cursor[i] = e;
        if (i == N - 1) offs[N] = boff + sm[t];
    }
}

// ================= scatter with 4 independent chains per thread =================
__global__ __launch_bounds__(256) void k_scatter(const int* __restrict__ ei, int E, int EN,
                                                 int* __restrict__ cursor, int* __restrict__ csr_eid) {
    int i = blockIdx.x * 1024 + threadIdx.x;
    int e0 = i, e1 = i + 256, e2 = i + 512, e3 = i + 768;
    bool v0 = e0 < EN, v1 = e1 < EN, v2 = e2 < EN, v3 = e3 < EN;
    int d0 = v0 ? ((e0 < E) ? ei[E + e0] : e0 - E) : 0;
    int d1 = v1 ? ((e1 < E) ? ei[E + e1] : e1 - E) : 0;
    int d2 = v2 ? ((e2 < E) ? ei[E + e2] : e2 - E) : 0;
    int d3 = v3 ? ((e3 < E) ? ei[E + e3] : e3 - E) : 0;
    int p0 = v0 ? atomicAdd(&cursor[d0], 1) : 0;
    int p1 = v1 ? atomicAdd(&cursor[d1], 1) : 0;
    int p2 = v2 ? atomicAdd(&cursor[d2], 1) : 0;
    int p3 = v3 ? atomicAdd(&cursor[d3], 1) : 0;
    if (v0) csr_eid[p0] = e0;
    if (v1) csr_eid[p1] = e1;
    if (v2) csr_eid[p2] = e2;
    if (v3) csr_eid[p3] = e3;
}

// ================= device bodies for gemm / sort_gather =================
__device__ __forceinline__ void gemm_dev(int bid,
    const unsigned short* __restrict__ A16, const unsigned short* __restrict__ Bt16, int M,
    const float* __restrict__ asf, const float* __restrict__ adf,
    unsigned short* __restrict__ C16, float* __restrict__ as_out, float* __restrict__ ad_out)
{
    __shared__ __align__(16) unsigned short Bsl[4 * 256 * 8]; // 16 KB
    int t = threadIdx.x;
    int lane = t & 63, w = t >> 6;
    int row0 = bid << 5;
    int kg = lane >> 4, fr = lane & 15;

    int ar0 = row0 + fr;      if (ar0 >= M) ar0 = 0;
    int ar1 = row0 + 16 + fr; if (ar1 >= M) ar1 = 0;
    const unsigned short* ap0 = A16 + (size_t)ar0 * 256 + (kg << 3);
    const unsigned short* ap1 = A16 + (size_t)ar1 * 256 + (kg << 3);

    f32x4 acc[2][4];
#pragma unroll
    for (int i = 0; i < 2; i++)
#pragma unroll
        for (int j = 0; j < 4; j++) acc[i][j] = (f32x4){0.f, 0.f, 0.f, 0.f};

    for (int ks = 0; ks < 8; ks++) {
#pragma unroll
        for (int j = 0; j < 4; j++) {
            __builtin_amdgcn_global_load_lds(
                (glob_b*)(Bt16 + (size_t)ks * 8192 + j * 2048 + t * 8),
                (lds_b*)((char*)Bsl + j * 4096 + t * 16),
                16, 0, 0);
        }
        bf16x8 a0 = *(const bf16x8*)(ap0 + (ks << 5));
        bf16x8 a1 = *(const bf16x8*)(ap1 + (ks << 5));
        __syncthreads();
#pragma unroll
        for (int nf = 0; nf < 4; nf++) {
            int col = (w << 6) + (nf << 4) + fr;
            bf16x8 bv = *(const bf16x8*)((const char*)Bsl + (kg << 12) + (((col << 4)) ^ (kg << 4)));
            acc[0][nf] = __builtin_amdgcn_mfma_f32_16x16x32_bf16(a0, bv, acc[0][nf], 0, 0, 0);
            acc[1][nf] = __builtin_amdgcn_mfma_f32_16x16x32_bf16(a1, bv, acc[1][nf], 0, 0, 0);
        }
        __syncthreads();
    }

#pragma unroll
    for (int mf = 0; mf < 2; mf++)
#pragma unroll
        for (int j = 0; j < 4; j++) {
            int gr = row0 + mf * 16 + kg * 4 + j;
            if (gr < M) {
#pragma unroll
                for (int nf = 0; nf < 4; nf++)
                    C16[(size_t)gr * 256 + (w << 6) + (nf << 4) + fr] = f2bf(acc[mf][nf][j]);
            }
        }
    float asv[4], adv[4];
#pragma unroll
    for (int nf = 0; nf < 4; nf++) {
        int col = (w << 6) + (nf << 4) + fr;
        asv[nf] = asf[col]; adv[nf] = adf[col];
    }
#pragma unroll
    for (int mf = 0; mf < 2; mf++)
#pragma unroll
        for (int j = 0; j < 4; j++) {
            float ps = acc[mf][0][j] * asv[0] + acc[mf][1][j] * asv[1] + acc[mf][2][j] * asv[2] + acc[mf][3][j] * asv[3];
            float pd = acc[mf][0][j] * adv[0] + acc[mf][1][j] * adv[1] + acc[mf][2][j] * adv[2] + acc[mf][3][j] * adv[3];
#pragma unroll
            for (int o = 1; o < 16; o <<= 1) { ps += __shfl_xor(ps, o); pd += __shfl_xor(pd, o); }
            if (fr == 0) {
                int gr = row0 + mf * 16 + kg * 4 + j;
                if (gr < M) {
                    as_out[gr * 4 + w] = ps;
                    ad_out[gr * 4 + w] = pd;
                }
            }
        }
}

__device__ __forceinline__ void sort_gather_dev(int bid, const int* __restrict__ offs, int* __restrict__ eid,
                                                const int* __restrict__ ei, const float* __restrict__ ew,
                                                const float* __restrict__ sumw, int E, int N,
                                                int* __restrict__ csr_src, float* __restrict__ csr_w) {
    int lane = threadIdx.x & 63;
    int n = (bid << 2) + (threadIdx.x >> 6);
    if (n >= N) return;
    int s0 = offs[n];
    int d = offs[n + 1] - s0;
    if (d <= 0) return;
    if (d <= 64) {
        int key = (lane < d) ? eid[s0 + lane] : 0x7fffffff;
        int rank = 0;
        for (int j = 0; j < d; j++) {
            int kj = __shfl(key, j);
            rank += (kj < key) ? 1 : 0;
        }
        if (lane < d) {
            int s; float wv;
            if (key < E) { s = ei[key]; wv = ew[key]; }
            else         { s = key - E; wv = *sumw / (float)E; }
            csr_src[s0 + rank] = s;
            csr_w[s0 + rank] = wv;
        }
    } else {
        if (lane == 0) {
            for (int i = s0 + 1; i < s0 + d; i++) {
                int ke = eid[i];
                int j = i - 1;
                while (j >= s0 && eid[j] > ke) { eid[j + 1] = eid[j]; j--; }
                eid[j + 1] = ke;
            }
        }
        __builtin_amdgcn_wave_barrier();
        for (int i = lane; i < d; i += 64) {
            int e = eid[s0 + i];
            int s; float wv;
            if (e < E) { s = ei[e]; wv = ew[e]; }
            else       { s = e - E; wv = *sumw / (float)E; }
            csr_src[s0 + i] = s;
            csr_w[s0 + i] = wv;
        }
    }
}

// ================= merged: gemm layer-1 + sort_gather =================
__global__ __launch_bounds__(256) void k_gemm_sort(int MB,
    const unsigned short* __restrict__ A16, const unsigned short* __restrict__ Bt16, int M,
    const float* __restrict__ asf, const float* __restrict__ adf,
    unsigned short* __restrict__ C16, float* __restrict__ as_out, float* __restrict__ ad_out,
    const int* __restrict__ offs, int* __restrict__ eid,
    const int* __restrict__ ei, const float* __restrict__ ew,
    const float* __restrict__ sumw, int E,
    int* __restrict__ csr_src, float* __restrict__ csr_w) {
    if ((int)blockIdx.x < MB)
        gemm_dev(blockIdx.x, A16, Bt16, M, asf, adf, C16, as_out, ad_out);
    else
        sort_gather_dev(blockIdx.x - MB, offs, eid, ei, ew, sumw, E, M, csr_src, csr_w);
}

// ================= standalone gemm (layer 2) =================
__global__ __launch_bounds__(256) void gemm_mfma(
    const unsigned short* __restrict__ A16, const unsigned short* __restrict__ Bt16, int M,
    const float* __restrict__ asf, const float* __restrict__ adf,
    unsigned short* __restrict__ C16, float* __restrict__ as_out, float* __restrict__ ad_out) {
    gemm_dev(blockIdx.x, A16, Bt16, M, asf, adf, C16, as_out, ad_out);
}

// ================= fused GAT + bias + LN + ELU -> bf16 out =================
#define ACC8(u, q) do { \
    acc0 += (q) * bf2f_lo((u).x); acc1 += (q) * bf2f_hi((u).x); \
    acc2 += (q) * bf2f_lo((u).y); acc3 += (q) * bf2f_hi((u).y); \
    acc4 += (q) * bf2f_lo((u).z); acc5 += (q) * bf2f_hi((u).z); \
    acc6 += (q) * bf2f_lo((u).w); acc7 += (q) * bf2f_hi((u).w); } while (0)

__global__ __launch_bounds__(256) void gat_kernel(
    const unsigned short* __restrict__ xp16, const int* __restrict__ offs,
    const int* __restrict__ csr_src, const float* __restrict__ csr_w,
    const float* __restrict__ as_, const float* __restrict__ ad_,
    const float* __restrict__ cvec, const float* __restrict__ bias,
    const float* __restrict__ ln_g, const float* __restrict__ ln_b,
    int N, unsigned short* __restrict__ out16) {
    __shared__ float p_lds[4][256];
    __shared__ int   s_lds[4][64];
    int lane = threadIdx.x & 63;
    int wid = threadIdx.x >> 6;
    int n = (blockIdx.x << 2) + wid;
    if (n >= N) return;
    int start = offs[n], end = offs[n + 1];
    int e0 = lane >> 5;
    int colb = lane & 31;
    int hq2 = colb >> 3;
    const unsigned short* xbase = xp16 + (size_t)colb * 8;
    float4 adv = *(const float4*)(ad_ + (size_t)n * 4);
    float c0 = cvec[0], c1 = cvec[1], c2 = cvec[2], c3 = cvec[3];
    float m = -INFINITY, dn = 0.f;
    float acc0 = 0, acc1 = 0, acc2 = 0, acc3 = 0, acc4 = 0, acc5 = 0, acc6 = 0, acc7 = 0;

    for (int base = start; base < end; base += 64) {
        int idx = base + lane;
        bool act = idx < end;
        int s = act ? csr_src[idx] : 0;
        float w = act ? csr_w[idx] : 0.f;
        float4 av = *(const float4*)(as_ + (size_t)s * 4);
        float l0 = av.x + adv.x + w * c0; l0 = l0 >= 0.f ? l0 : NEG_SLOPE * l0;
        float l1 = av.y + adv.y + w * c1; l1 = l1 >= 0.f ? l1 : NEG_SLOPE * l1;
        float l2 = av.z + adv.z + w * c2; l2 = l2 >= 0.f ? l2 : NEG_SLOPE * l2;
        float l3 = av.w + adv.w + w * c3; l3 = l3 >= 0.f ? l3 : NEG_SLOPE * l3;
        float lm = fmaxf(fmaxf(l0, l1), fmaxf(l2, l3));
        if (!act) lm = -INFINITY;
        for (int o = 32; o; o >>= 1) lm = fmaxf(lm, __shfl_xor(lm, o));
        float nm = fmaxf(m, lm);
        float sc = __expf(m - nm);
        m = nm;
        dn *= sc;
        acc0 *= sc; acc1 *= sc; acc2 *= sc; acc3 *= sc;
        acc4 *= sc; acc5 *= sc; acc6 *= sc; acc7 *= sc;
        float p0 = act ? __expf(l0 - m) : 0.f;
        float p1 = act ? __expf(l1 - m) : 0.f;
        float p2 = act ? __expf(l2 - m) : 0.f;
        float p3 = act ? __expf(l3 - m) : 0.f;
        float4 pv = { p0, p1, p2, p3 };
        *(float4*)&p_lds[wid][lane << 2] = pv;
        s_lds[wid][lane] = s;
        int cnt = end - base; if (cnt > 64) cnt = 64;
        int k = 0;
        for (; k + 8 <= cnt; k += 8) {
            int i0 = k + e0, i1 = k + 2 + e0, i2 = k + 4 + e0, i3 = k + 6 + e0;
            int s0 = s_lds[wid][i0], s1 = s_lds[wid][i1], s2 = s_lds[wid][i2], s3 = s_lds[wid][i3];
            uint4 u0 = *(const uint4*)(xbase + (size_t)s0 * 256);
            uint4 u1 = *(const uint4*)(xbase + (size_t)s1 * 256);
            uint4 u2 = *(const uint4*)(xbase + (size_t)s2 * 256);
            uint4 u3 = *(const uint4*)(xbase + (size_t)s3 * 256);
            float q0 = p_lds[wid][(i0 << 2) + hq2];
            float q1 = p_lds[wid][(i1 << 2) + hq2];
            float q2 = p_lds[wid][(i2 << 2) + hq2];
            float q3 = p_lds[wid][(i3 << 2) + hq2];
            dn += q0 + q1 + q2 + q3;
            ACC8(u0, q0); ACC8(u1, q1); ACC8(u2, q2); ACC8(u3, q3);
        }
        for (; k < cnt; k += 2) {
            int i = k + e0;
            bool v = i < cnt;
            int si = s_lds[wid][v ? i : 0];
            float qi = v ? p_lds[wid][(i << 2) + hq2] : 0.f;
            uint4 u = *(const uint4*)(xbase + (size_t)si * 256);
            dn += qi;
            ACC8(u, qi);
        }
    }
    acc0 += __shfl_xor(acc0, 32); acc1 += __shfl_xor(acc1, 32);
    acc2 += __shfl_xor(acc2, 32); acc3 += __shfl_xor(acc3, 32);
    acc4 += __shfl_xor(acc4, 32); acc5 += __shfl_xor(acc5, 32);
    acc6 += __shfl_xor(acc6, 32); acc7 += __shfl_xor(acc7, 32);
    dn += __shfl_xor(dn, 32);
    float inv = 1.f / dn;
    int cb8 = colb << 3;
    float4 bA = *(const float4*)(bias + cb8);
    float4 bB = *(const float4*)(bias + cb8 + 4);
    float o0 = acc0 * inv + bA.x, o1 = acc1 * inv + bA.y, o2 = acc2 * inv + bA.z, o3 = acc3 * inv + bA.w;
    float o4 = acc4 * inv + bB.x, o5 = acc5 * inv + bB.y, o6 = acc6 * inv + bB.z, o7 = acc7 * inv + bB.w;
    float part = ((o0 + o1) + (o2 + o3)) + ((o4 + o5) + (o6 + o7));
    for (int o = 16; o; o >>= 1) part += __shfl_xor(part, o);
    float mu = part * (1.f / 256.f);
    float d0 = o0 - mu, d1 = o1 - mu, d2 = o2 - mu, d3 = o3 - mu;
    float d4 = o4 - mu, d5 = o5 - mu, d6 = o6 - mu, d7 = o7 - mu;
    float vpart = ((d0 * d0 + d1 * d1) + (d2 * d2 + d3 * d3)) + ((d4 * d4 + d5 * d5) + (d6 * d6 + d7 * d7));
    for (int o = 16; o; o >>= 1) vpart += __shfl_xor(vpart, o);
    float rstd = rsqrtf(vpart * (1.f / 256.f) + LN_EPS);
    float4 gA = *(const float4*)(ln_g + cb8), gB = *(const float4*)(ln_g + cb8 + 4);
    float4 eA = *(const float4*)(ln_b + cb8), eB = *(const float4*)(ln_b + cb8 + 4);
    float y0 = d0 * rstd * gA.x + eA.x; y0 = y0 > 0.f ? y0 : __expf(y0) - 1.f;
    float y1 = d1 * rstd * gA.y + eA.y; y1 = y1 > 0.f ? y1 : __expf(y1) - 1.f;
    float y2 = d2 * rstd * gA.z + eA.z; y2 = y2 > 0.f ? y2 : __expf(y2) - 1.f;
    float y3 = d3 * rstd * gA.w + eA.w; y3 = y3 > 0.f ? y3 : __expf(y3) - 1.f;
    float y4 = d4 * rstd * gB.x + eB.x; y4 = y4 > 0.f ? y4 : __expf(y4) - 1.f;
    float y5 = d5 * rstd * gB.y + eB.y; y5 = y5 > 0.f ? y5 : __expf(y5) - 1.f;
    float y6 = d6 * rstd * gB.z + eB.z; y6 = y6 > 0.f ? y6 : __expf(y6) - 1.f;
    float y7 = d7 * rstd * gB.w + eB.w; y7 = y7 > 0.f ? y7 : __expf(y7) - 1.f;
    if (lane < 32) {
        uint4 ov;
        ov.x = ((unsigned int)f2bf(y1) << 16) | f2bf(y0);
        ov.y = ((unsigned int)f2bf(y3) << 16) | f2bf(y2);
        ov.z = ((unsigned int)f2bf(y5) << 16) | f2bf(y4);
        ov.w = ((unsigned int)f2bf(y7) << 16) | f2bf(y6);
        *(uint4*)(out16 + (size_t)n * HID + cb8) = ov;
    }
}

// ================= batch mean pool (bf16 input), 4-way unrolled =================
__device__ __forceinline__ int lower_bound_i(const int* a, int n, int key) {
    int lo = 0, hi = n;
    while (lo < hi) { int mid = (lo + hi) >> 1; if (a[mid] < key) lo = mid + 1; else hi = mid; }
    return lo;
}

__global__ __launch_bounds__(256) void pool_kernel(const unsigned short* __restrict__ h, const int* __restrict__ batch,
                                                   int N, float* __restrict__ out) {
    int b = blockIdx.x;
    int lo = lower_bound_i(batch, N, b);
    int hi = lower_bound_i(batch, N, b + 1);
    float a0 = 0.f, a1 = 0.f, a2 = 0.f, a3 = 0.f;
    int n = lo;
    for (; n + 4 <= hi; n += 4) {
        a0 += bf2f_u(h[(size_t)(n + 0) * HID + threadIdx.x]);
        a1 += bf2f_u(h[(size_t)(n + 1) * HID + threadIdx.x]);
        a2 += bf2f_u(h[(size_t)(n + 2) * HID + threadIdx.x]);
        a3 += bf2f_u(h[(size_t)(n + 3) * HID + threadIdx.x]);
    }
    for (; n < hi; n++) a0 += bf2f_u(h[(size_t)n * HID + threadIdx.x]);
    float acc = (a0 + a1) + (a2 + a3);
    out[(size_t)b * HID + threadIdx.x] = acc / fmaxf((float)(hi - lo), 1.f);
}

extern "C" void kernel_launch(void* const* d_in, const int* in_sizes, int n_in,
                              void* d_out, int out_size, void* d_ws, size_t ws_size,
                              hipStream_t stream) {
    const float* x    = (const float*)d_in[0];
    const int*   ei   = (const int*)d_in[1];
    const float* ew   = (const float*)d_in[2];
    const int*   batch= (const int*)d_in[3];
    const float* W1   = (const float*)d_in[4];
    const float* as1  = (const float*)d_in[5];
    const float* ad1  = (const float*)d_in[6];
    const float* ae1  = (const float*)d_in[7];
    const float* We1  = (const float*)d_in[8];
    const float* b1   = (const float*)d_in[9];
    const float* W2   = (const float*)d_in[10];
    const float* as2  = (const float*)d_in[11];
    const float* ad2  = (const float*)d_in[12];
    const float* ae2  = (const float*)d_in[13];
    const float* We2  = (const float*)d_in[14];
    const float* b2   = (const float*)d_in[15];
    const float* ln1g = (const float*)d_in[16];
    const float* ln1b = (const float*)d_in[17];
    const float* ln2g = (const float*)d_in[18];
    const float* ln2b = (const float*)d_in[19];

    int N = in_sizes[3];
    int E = in_sizes[2];
    int FIN = in_sizes[0] / N;
    int EN = E + N;
    int B = out_size / HID;
    float* outp = (float*)d_out;
    int NB = (N + 255) / 256;          // <= 256 required (N=50000 -> 196)
    int NH = (EN + 1023) / 1024;       // 4-edge-ILP blocks

    char* ws = (char*)d_ws;
    size_t off = 0;
    auto alloc = [&](size_t bytes) { void* p = ws + off; off = (off + bytes + 255) & ~(size_t)255; return p; };
    float* sumw    = (float*)alloc(4);
    int*   deg     = (int*)  alloc((size_t)N * 4);           // zeroed region = [0, 256 + N*4)
    size_t zero_bytes = 256 + (size_t)N * 4;
    float* partials= (float*)alloc(256 * 4);
    int*   bsum    = (int*)  alloc(256 * 4);
    int*   offs    = (int*)  alloc((size_t)(N + 1) * 4);
    int*   cursor  = (int*)  alloc((size_t)N * 4);
    int*   csr_eid = (int*)  alloc((size_t)EN * 4);
    int*   csr_src = (int*)  alloc((size_t)EN * 4);
    float* csr_w   = (float*)alloc((size_t)EN * 4);
    float* asb     = (float*)alloc((size_t)N * 4 * 4);
    float* adb     = (float*)alloc((size_t)N * 4 * 4);
    float* cc      = (float*)alloc(64);
    unsigned short* w1_16 = (unsigned short*)alloc((size_t)HID * HID * 2);
    unsigned short* w2_16 = (unsigned short*)alloc((size_t)HID * HID * 2);
    unsigned short* x16   = (unsigned short*)alloc((size_t)N * HID * 2);  // x -> h1 -> h2 (reused)
    unsigned short* xp16  = (unsigned short*)alloc((size_t)N * HID * 2);
    (void)ws_size; (void)n_in;

    int MB = (N + 31) / 32;

    (void)hipMemsetAsync(d_ws, 0, zero_bytes, stream);
    k_pre<<<256 + NH + 512 + N, 256, 0, stream>>>(ew, E, ei, N, EN, NH, partials, deg,
                                                  W1, W2, w1_16, w2_16, FIN, x, x16, FIN);
    k_scanred_coeff<<<NB + 2, 256, 0, stream>>>(deg, N, NB, bsum, partials, sumw, We1, ae1, We2, ae2, cc, cc + 4);
    k_scan_apply<<<NB, 256, 0, stream>>>(deg, N, NB, bsum, offs, cursor);
    k_scatter<<<(EN + 1023) / 1024, 256, 0, stream>>>(ei, E, EN, cursor, csr_eid);
    // layer 1 gemm + sort_gather (independent work, one grid)
    k_gemm_sort<<<MB + (N + 3) / 4, 256, 0, stream>>>(MB, x16, w1_16, N, as1, ad1, xp16, asb, adb,
                                                      offs, csr_eid, ei, ew, sumw, E, csr_src, csr_w);
    gat_kernel<<<(N + 3) / 4, 256, 0, stream>>>(xp16, offs, csr_src, csr_w, asb, adb, cc, b1, ln1g, ln1b, N, x16);
    // layer 2
    gemm_mfma<<<MB, 256, 0, stream>>>(x16, w2_16, N, as2, ad2, xp16, asb, adb);
    gat_kernel<<<(N + 3) / 4, 256, 0, stream>>>(xp16, offs, csr_src, csr_w, asb, adb, cc + 4, b2, ln2g, ln2b, N, x16);
    // pool
    pool_kernel<<<B, 256, 0, stream>>>(x16, batch, N, outp);
}